// Round 10
// baseline (456.615 us; speedup 1.0000x reference)
//
#include <hip/hip_runtime.h>
#include <math.h>

#define BN_EPS 1e-5f
constexpr int CAP = 64;     // max neighbors/node incl self-loop
constexpr int BSH = 9;      // dst-bucket shift: 512 nodes / bucket
constexpr int BCAP = 10240; // entries per bucket

typedef __attribute__((ext_vector_type(8))) short bf16x8;
typedef __attribute__((ext_vector_type(4))) float f32x4;

// ---- bf16 helpers (round-to-nearest-even) ----
__device__ inline unsigned short f2bf(float f) {
    unsigned u = __float_as_uint(f);
    return (unsigned short)((u + 0x7fffu + ((u >> 16) & 1u)) >> 16);
}
__device__ inline unsigned pack2bf(float x, float y) {
    return (unsigned)f2bf(x) | ((unsigned)f2bf(y) << 16);
}
__device__ inline float2 bf2_to_f2(unsigned v) {
    float2 r;
    r.x = __uint_as_float(v << 16);
    r.y = __uint_as_float(v & 0xffff0000u);
    return r;
}
__device__ inline void addu2(float* a, uint2 v) {
    float2 x0 = bf2_to_f2(v.x), x1 = bf2_to_f2(v.y);
    a[0] += x0.x; a[1] += x0.y; a[2] += x1.x; a[3] += x1.y;
}

// ---------------- graph build: dst-binned counting sort (id space) ----------------
__global__ __launch_bounds__(256) void k_zero(int* __restrict__ buf, int L) {
    int i = blockIdx.x * 256 + threadIdx.x;
    if (i < L) buf[i] = 0;
}

__global__ __launch_bounds__(256) void k_bin(const int* __restrict__ ei, int E, int K,
                                             uint2* __restrict__ bins, int* __restrict__ bcnt) {
    __shared__ int hist[256];
    __shared__ int lbase[256];
    const int tid = threadIdx.x;
    const int e0 = blockIdx.x * 2048;
    hist[tid] = 0;
    __syncthreads();
    int s[8], d[8];
    bool m[8];
#pragma unroll
    for (int i = 0; i < 8; ++i) {
        int e = e0 + i * 256 + tid;
        m[i] = e < E;
        s[i] = m[i] ? ei[e] : 0;
        d[i] = m[i] ? ei[E + e] : 0;
        if (m[i]) atomicAdd(&hist[d[i] >> BSH], 1);
    }
    __syncthreads();
    if (tid < K && hist[tid] > 0) lbase[tid] = atomicAdd(&bcnt[tid], hist[tid]);
    __syncthreads();
    hist[tid] = 0;
    __syncthreads();
#pragma unroll
    for (int i = 0; i < 8; ++i) {
        if (m[i]) {
            int b = d[i] >> BSH;
            int pos = lbase[b] + atomicAdd(&hist[b], 1);
            if (pos < BCAP) bins[(size_t)b * BCAP + pos] = make_uint2((unsigned)s[i], (unsigned)d[i]);
        }
    }
}

__global__ __launch_bounds__(1024) void k_place(const uint2* __restrict__ bins,
                                                const int* __restrict__ bcnt,
                                                int* __restrict__ col, int* __restrict__ cnt,
                                                float* __restrict__ dinv, int* __restrict__ dhist,
                                                int N) {
    const int b = blockIdx.x;
    const int node0 = b << BSH;
    const int nn = min(1 << BSH, N - node0);
    __shared__ int c2[1 << BSH];
    __shared__ int lh[CAP + 2];
    const int tid = threadIdx.x;
    if (tid < CAP + 2) lh[tid] = 0;
    for (int i = tid; i < nn; i += 1024) {
        c2[i] = 1;
        col[(size_t)(node0 + i) * CAP] = node0 + i;
    }
    __syncthreads();
    const int nb = min(bcnt[b], BCAP);
    const uint2* __restrict__ bb = bins + (size_t)b * BCAP;
    for (int i = tid; i < nb; i += 1024) {
        uint2 e = bb[i];
        int pos = atomicAdd(&c2[(int)e.y - node0], 1);
        if (pos < CAP) col[(size_t)e.y * CAP + pos] = (int)e.x;
    }
    __syncthreads();
    for (int i = tid; i < nn; i += 1024) {
        int c = c2[i];
        cnt[node0 + i] = c;
        dinv[node0 + i] = rsqrtf((float)c);
        atomicAdd(&lh[min(c, CAP)], 1);
    }
    __syncthreads();
    if (tid <= CAP && lh[tid] > 0) atomicAdd(&dhist[tid], lh[tid]);
}

// prefix over degree histogram, DESCENDING degree. doff/doff0 = slot band starts,
// ebase = edge-array band starts, sentinel = rowptr2[N].
__global__ void k_prefix(const int* __restrict__ dhist, int* __restrict__ doff,
                         int* __restrict__ doff0, int* __restrict__ ebase,
                         int* __restrict__ sentinel) {
    if (threadIdx.x == 0) {
        int s = 0, e = 0;
        for (int d = CAP; d >= 0; --d) {
            doff[d] = s; doff0[d] = s; ebase[d] = e;
            s += dhist[d]; e += dhist[d] * d;
        }
        *sentinel = e;
    }
}

__global__ __launch_bounds__(256) void k_scatter(const int* __restrict__ cnt, int* __restrict__ doff,
                                                 int* __restrict__ perm, int N) {
    __shared__ int lh[CAP + 2];
    __shared__ int lbase[CAP + 2];
    __shared__ int lpos[CAP + 2];
    const int tid = threadIdx.x;
    if (tid < CAP + 2) { lh[tid] = 0; lpos[tid] = 0; }
    __syncthreads();
    const int i = blockIdx.x * 256 + tid;
    const bool act = i < N;
    int b = 0;
    if (act) { b = min(cnt[i], CAP); atomicAdd(&lh[b], 1); }
    __syncthreads();
    if (tid <= CAP && lh[tid] > 0) lbase[tid] = atomicAdd(&doff[tid], lh[tid]);
    __syncthreads();
    if (act) {
        int p = atomicAdd(&lpos[b], 1);
        perm[lbase[b] + p] = i;
    }
}

__global__ __launch_bounds__(256) void k_iperm(const int* __restrict__ perm, int* __restrict__ iperm, int N) {
    int i = blockIdx.x * 256 + threadIdx.x;
    if (i < N) iperm[perm[i]] = i;
}

// relabel to slot space: compact CSR col2 (slot entries), rowptr2, dinv2
__global__ __launch_bounds__(256) void k_relabel(
    const int* __restrict__ perm, const int* __restrict__ iperm,
    const int* __restrict__ cnt, const float* __restrict__ dinv,
    const int* __restrict__ col, const int* __restrict__ doff0, const int* __restrict__ ebase,
    int* __restrict__ col2, int* __restrict__ rowptr2, float* __restrict__ dinv2, int N)
{
    int slot = blockIdx.x * 256 + threadIdx.x;
    if (slot >= N) return;
    int id = perm[slot];
    int d = min(cnt[id], CAP);
    int off = ebase[d] + (slot - doff0[d]) * d;
    rowptr2[slot] = off;
    dinv2[slot] = dinv[id];
    const int* cr = col + (size_t)id * CAP;
    for (int p = 0; p < d; ++p) col2[off + p] = iperm[cr[p]];
}

// ---------------- weight repack: fp32 [FIN][FOUT] -> bf16 fragment-linear ----------------
__global__ __launch_bounds__(256) void k_repack(
    const float* __restrict__ w_in, const float* __restrict__ w1,
    const float* __restrict__ w2, const float* __restrict__ w3,
    unsigned short* __restrict__ f_in, unsigned short* __restrict__ f1,
    unsigned short* __restrict__ f2, unsigned short* __restrict__ f3)
{
    int idx = blockIdx.x * 256 + threadIdx.x;
    const float* src;
    unsigned short* dst;
    int FOUT, local;
    if (idx < 8192)       { src = w_in; dst = f_in; FOUT = 64;  local = idx; }
    else if (idx < 16384) { src = w1;   dst = f1;   FOUT = 128; local = idx - 8192; }
    else if (idx < 32768) { src = w2;   dst = f2;   FOUT = 128; local = idx - 16384; }
    else                  { src = w3;   dst = f3;   FOUT = 64;  local = idx - 32768; }
    int k = local / FOUT, n = local % FOUT;
    int NT = FOUT >> 4;
    dst[((((k >> 5) * NT + (n >> 4)) * 64) + ((k >> 3) & 3) * 16 + (n & 15)) * 8 + (k & 7)] = f2bf(src[local]);
}

// ---------------- sliced aggregation: out_s[s][i][SD] = dinv2[i] * sum_j hin_s[s][c[j]][SD] ----------------
// slice = blockIdx & 7 -> one XCD per slice (round-robin dispatch) -> panel (<=3.2MB) L2-resident.
template <int F>
__global__ __launch_bounds__(256) void k_agg(
    const unsigned short* __restrict__ hin_s, unsigned short* __restrict__ out_s,
    const int* __restrict__ col2, const int* __restrict__ rowptr2,
    const float* __restrict__ dinv2, int N)
{
    constexpr int SD = F / 8;       // dims per slice
    constexpr int LPN = SD / 4;     // lanes per node (uint2 = 4 dims)
    constexpr int NPW = 64 / LPN;   // nodes per wave
    constexpr int NPP = 4 * NPW;    // nodes per block-pass
    constexpr int PASSES = 256 / NPP;
    const int s = blockIdx.x & 7, chunk = blockIdx.x >> 3;
    const int tid = threadIdx.x, wid = tid >> 6, lane = tid & 63;
    const int g = lane / LPN, l = lane % LPN;
    const unsigned short* __restrict__ panel = hin_s + (size_t)s * N * SD;
    unsigned short* __restrict__ opanel = out_s + (size_t)s * N * SD;

#pragma unroll
    for (int pass = 0; pass < PASSES; ++pass) {
        int slot = chunk * 256 + pass * NPP + wid * NPW + g;
        if (slot < N) {
            int off = rowptr2[slot];
            int n = rowptr2[slot + 1] - off;
            const int* __restrict__ cr = col2 + off;
            float acc[4] = {0.f, 0.f, 0.f, 0.f};
            int p = 0;
            for (; p + 8 <= n; p += 8) {
                int c0 = cr[p], c1 = cr[p + 1], c2 = cr[p + 2], c3 = cr[p + 3];
                int c4 = cr[p + 4], c5 = cr[p + 5], c6 = cr[p + 6], c7 = cr[p + 7];
                uint2 v0 = *(const uint2*)(panel + (size_t)c0 * SD + l * 4);
                uint2 v1 = *(const uint2*)(panel + (size_t)c1 * SD + l * 4);
                uint2 v2 = *(const uint2*)(panel + (size_t)c2 * SD + l * 4);
                uint2 v3 = *(const uint2*)(panel + (size_t)c3 * SD + l * 4);
                uint2 v4 = *(const uint2*)(panel + (size_t)c4 * SD + l * 4);
                uint2 v5 = *(const uint2*)(panel + (size_t)c5 * SD + l * 4);
                uint2 v6 = *(const uint2*)(panel + (size_t)c6 * SD + l * 4);
                uint2 v7 = *(const uint2*)(panel + (size_t)c7 * SD + l * 4);
                addu2(acc, v0); addu2(acc, v1); addu2(acc, v2); addu2(acc, v3);
                addu2(acc, v4); addu2(acc, v5); addu2(acc, v6); addu2(acc, v7);
            }
            for (; p + 2 <= n; p += 2) {
                int c0 = cr[p], c1 = cr[p + 1];
                uint2 v0 = *(const uint2*)(panel + (size_t)c0 * SD + l * 4);
                uint2 v1 = *(const uint2*)(panel + (size_t)c1 * SD + l * 4);
                addu2(acc, v0); addu2(acc, v1);
            }
            if (p < n) {
                uint2 v0 = *(const uint2*)(panel + (size_t)cr[p] * SD + l * 4);
                addu2(acc, v0);
            }
            float di = dinv2[slot];
            uint2 o;
            o.x = pack2bf(acc[0] * di, acc[1] * di);
            o.y = pack2bf(acc[2] * di, acc[3] * di);
            *(uint2*)(opanel + (size_t)slot * SD + l * 4) = o;
        }
    }
}

// ---------------- layer 0: h0_s = sliced bf16( dinv2 * relu(x[perm] @ w_in + b_in) ) ----------------
__global__ __launch_bounds__(256) void mfma_gemm0(
    const float* __restrict__ x, const unsigned short* __restrict__ wfrag,
    const float* __restrict__ bias, const float* __restrict__ dinv2,
    const int* __restrict__ perm,
    unsigned short* __restrict__ h0s, int N)
{
    constexpr int FIN = 128, KS = 4, NT = 4, OST = 72;
    __shared__ unsigned short otile[4 * 16 * OST];
    __shared__ float ct[64];
    __shared__ int lperm[64];
    const int tid = threadIdx.x;
    if (tid < 64) {
        ct[tid] = bias[tid];
        lperm[tid] = perm[min((int)(blockIdx.x * 64 + tid), N - 1)];
    }
    __syncthreads();

    const int wid = tid >> 6, lane = tid & 63, q = lane >> 4, m = lane & 15;
    const int rowbase = blockIdx.x * 64 + wid * 16;
    const int id = lperm[wid * 16 + m];
    const bf16x8* __restrict__ wf = (const bf16x8*)wfrag;

    f32x4 accm[NT];
#pragma unroll
    for (int nt = 0; nt < NT; ++nt) accm[nt] = (f32x4){0.f, 0.f, 0.f, 0.f};
#pragma unroll
    for (int ks = 0; ks < KS; ++ks) {
        const float* ap = x + (size_t)id * FIN + ks * 32 + q * 8;
        float4 a0 = *(const float4*)ap;
        float4 a1 = *(const float4*)(ap + 4);
        bf16x8 af;
        af[0] = (short)f2bf(a0.x); af[1] = (short)f2bf(a0.y);
        af[2] = (short)f2bf(a0.z); af[3] = (short)f2bf(a0.w);
        af[4] = (short)f2bf(a1.x); af[5] = (short)f2bf(a1.y);
        af[6] = (short)f2bf(a1.z); af[7] = (short)f2bf(a1.w);
#pragma unroll
        for (int nt = 0; nt < NT; ++nt)
            accm[nt] = __builtin_amdgcn_mfma_f32_16x16x32_bf16(af, wf[(ks * NT + nt) * 64 + lane], accm[nt], 0, 0, 0);
    }

    unsigned short* ot = otile + wid * 16 * OST;
    float rs[4];
#pragma unroll
    for (int r = 0; r < 4; ++r) rs[r] = dinv2[min(rowbase + q * 4 + r, N - 1)];
#pragma unroll
    for (int nt = 0; nt < NT; ++nt) {
        int c = nt * 16 + m;
        float t = ct[c];
#pragma unroll
        for (int r = 0; r < 4; ++r) {
            float z = fmaxf(accm[nt][r] + t, 0.f);
            ot[(q * 4 + r) * OST + c] = f2bf(z * rs[r]);
        }
    }
#pragma unroll
    for (int idx = lane; idx < 16 * 8; idx += 64) {
        int row = idx >> 3, sl = idx & 7;
        int gr = rowbase + row;
        if (gr < N)
            *(uint4*)(h0s + ((size_t)sl * N + gr) * 8) = *(const uint4*)&ot[row * OST + sl * 8];
    }
}

// ---------------- layer 1: h1_s = sliced bf16( dinv2 * relu(bn1(a1 @ w1 + b1)) ) ----------------
__global__ __launch_bounds__(256) void mfma_gemm1(
    const unsigned short* __restrict__ a1s, const unsigned short* __restrict__ wfrag,
    const float* __restrict__ bias, const float* __restrict__ g, const float* __restrict__ beta,
    const float* __restrict__ mm, const float* __restrict__ vv,
    const float* __restrict__ dinv2,
    unsigned short* __restrict__ h1s, int N)
{
    constexpr int KS = 2, NT = 8, OST = 136;
    __shared__ unsigned short otile[4 * 16 * OST];
    __shared__ float cs[128], ct[128];
    const int tid = threadIdx.x;
    if (tid < 128) {
        float s = g[tid] * rsqrtf(vv[tid] + BN_EPS);
        cs[tid] = s;
        ct[tid] = bias[tid] * s + beta[tid] - mm[tid] * s;
    }
    __syncthreads();

    const int wid = tid >> 6, lane = tid & 63, q = lane >> 4, m = lane & 15;
    const int rowbase = blockIdx.x * 64 + wid * 16;
    const int rowc = min(rowbase + m, N - 1);
    const bf16x8* __restrict__ wf = (const bf16x8*)wfrag;

    bf16x8 af[KS];
#pragma unroll
    for (int ks = 0; ks < KS; ++ks)
        af[ks] = *(const bf16x8*)(a1s + ((size_t)(ks * 4 + q) * N + rowc) * 8);

    f32x4 accm[NT];
#pragma unroll
    for (int nt = 0; nt < NT; ++nt) accm[nt] = (f32x4){0.f, 0.f, 0.f, 0.f};
#pragma unroll
    for (int ks = 0; ks < KS; ++ks)
#pragma unroll
        for (int nt = 0; nt < NT; ++nt)
            accm[nt] = __builtin_amdgcn_mfma_f32_16x16x32_bf16(af[ks], wf[(ks * NT + nt) * 64 + lane], accm[nt], 0, 0, 0);

    unsigned short* ot = otile + wid * 16 * OST;
    float rs[4];
#pragma unroll
    for (int r = 0; r < 4; ++r) rs[r] = dinv2[min(rowbase + q * 4 + r, N - 1)];
#pragma unroll
    for (int nt = 0; nt < NT; ++nt) {
        int cc = nt * 16 + m;
        float s = cs[cc], t = ct[cc];
#pragma unroll
        for (int r = 0; r < 4; ++r) {
            float z = fmaxf(accm[nt][r] * s + t, 0.f);
            ot[(q * 4 + r) * OST + cc] = f2bf(z * rs[r]);
        }
    }
#pragma unroll
    for (int idx = lane; idx < 16 * 8; idx += 64) {
        int row = idx >> 3, sl = idx & 7;
        int gr = rowbase + row;
        if (gr < N) {
            unsigned short* dst = h1s + ((size_t)sl * N + gr) * 16;
            *(uint4*)dst = *(const uint4*)&ot[row * OST + sl * 16];
            *(uint4*)(dst + 8) = *(const uint4*)&ot[row * OST + sl * 16 + 8];
        }
    }
}

// ---------------- layers 2+3: t3_s = sliced bf16( dinv2 * (relu(bn2(a2@w2+b2)) @ w3) ) ----------------
__global__ __launch_bounds__(256) void mfma_gemm23(
    const unsigned short* __restrict__ a2s, const unsigned short* __restrict__ w2f,
    const float* __restrict__ b2, const float* __restrict__ g2, const float* __restrict__ beta2,
    const float* __restrict__ m2, const float* __restrict__ v2,
    const unsigned short* __restrict__ w3f, const float* __restrict__ dinv2,
    unsigned short* __restrict__ t3s, int N)
{
    constexpr int KS = 4, NT1 = 8, NT2 = 4, OST = 136, OST2 = 72;
    __shared__ unsigned short otile[4 * 16 * OST];
    __shared__ float cs[128], ct[128];
    const int tid = threadIdx.x;
    if (tid < 128) {
        float s = g2[tid] * rsqrtf(v2[tid] + BN_EPS);
        cs[tid] = s;
        ct[tid] = b2[tid] * s + beta2[tid] - m2[tid] * s;
    }
    __syncthreads();

    const int wid = tid >> 6, lane = tid & 63, q = lane >> 4, m = lane & 15;
    const int rowbase = blockIdx.x * 64 + wid * 16;
    const int rowc = min(rowbase + m, N - 1);

    bf16x8 af[KS];
#pragma unroll
    for (int ks = 0; ks < KS; ++ks)
        af[ks] = *(const bf16x8*)(a2s + ((size_t)(ks * 2 + (q >> 1)) * N + rowc) * 16 + (q & 1) * 8);

    f32x4 accm[NT1];
#pragma unroll
    for (int nt = 0; nt < NT1; ++nt) accm[nt] = (f32x4){0.f, 0.f, 0.f, 0.f};
    const bf16x8* __restrict__ wf2 = (const bf16x8*)w2f;
#pragma unroll
    for (int ks = 0; ks < KS; ++ks)
#pragma unroll
        for (int nt = 0; nt < NT1; ++nt)
            accm[nt] = __builtin_amdgcn_mfma_f32_16x16x32_bf16(af[ks], wf2[(ks * NT1 + nt) * 64 + lane], accm[nt], 0, 0, 0);

    unsigned short* ot = otile + wid * 16 * OST;
#pragma unroll
    for (int nt = 0; nt < NT1; ++nt) {
        int cc = nt * 16 + m;
        float s = cs[cc], t = ct[cc];
#pragma unroll
        for (int r = 0; r < 4; ++r) {
            float z = fmaxf(accm[nt][r] * s + t, 0.f);
            ot[(q * 4 + r) * OST + cc] = f2bf(z);
        }
    }
    bf16x8 af2[KS];
#pragma unroll
    for (int ks = 0; ks < KS; ++ks)
        af2[ks] = *(const bf16x8*)&ot[m * OST + ks * 32 + q * 8];

    f32x4 acc2[NT2];
#pragma unroll
    for (int nt = 0; nt < NT2; ++nt) acc2[nt] = (f32x4){0.f, 0.f, 0.f, 0.f};
    const bf16x8* __restrict__ wf3 = (const bf16x8*)w3f;
#pragma unroll
    for (int ks = 0; ks < KS; ++ks)
#pragma unroll
        for (int nt = 0; nt < NT2; ++nt)
            acc2[nt] = __builtin_amdgcn_mfma_f32_16x16x32_bf16(af2[ks], wf3[(ks * NT2 + nt) * 64 + lane], acc2[nt], 0, 0, 0);

    float rs[4];
#pragma unroll
    for (int r = 0; r < 4; ++r) rs[r] = dinv2[min(rowbase + q * 4 + r, N - 1)];
#pragma unroll
    for (int nt = 0; nt < NT2; ++nt) {
        int cc = nt * 16 + m;
#pragma unroll
        for (int r = 0; r < 4; ++r)
            ot[(q * 4 + r) * OST2 + cc] = f2bf(acc2[nt][r] * rs[r]);
    }
#pragma unroll
    for (int idx = lane; idx < 16 * 8; idx += 64) {
        int row = idx >> 3, sl = idx & 7;
        int gr = rowbase + row;
        if (gr < N)
            *(uint4*)(t3s + ((size_t)sl * N + gr) * 8) = *(const uint4*)&ot[row * OST2 + sl * 8];
    }
}

// ---------------- final: out[perm[slot]] = log_softmax( relu(bn3(a3 + b3)) @ w_out + b_out ) ----------------
__global__ __launch_bounds__(256) void k_final(
    const unsigned short* __restrict__ a3s, const int* __restrict__ perm,
    const float* __restrict__ b3, const float* __restrict__ g3, const float* __restrict__ beta3,
    const float* __restrict__ m3, const float* __restrict__ v3,
    const float* __restrict__ w_out, const float* __restrict__ b_out,
    float* __restrict__ out, int N)
{
    __shared__ float S[64], T[64], sw[64 * 8], sb[8];
    const int tid = threadIdx.x;
    if (tid < 64) {
        float s = g3[tid] * rsqrtf(v3[tid] + BN_EPS);
        S[tid] = s;
        T[tid] = b3[tid] * s + beta3[tid] - m3[tid] * s;
    }
    if (tid < 8) sb[tid] = b_out[tid];
    sw[tid] = w_out[tid];
    sw[tid + 256] = w_out[tid + 256];
    __syncthreads();

    const int slot = blockIdx.x * 256 + tid;
    if (slot >= N) return;

    float lg[8];
#pragma unroll
    for (int cc = 0; cc < 8; ++cc) lg[cc] = sb[cc];
#pragma unroll
    for (int sl = 0; sl < 8; ++sl) {
        uint4 v = *(const uint4*)(a3s + ((size_t)sl * N + slot) * 8);
        float2 p01 = bf2_to_f2(v.x), p23 = bf2_to_f2(v.y), p45 = bf2_to_f2(v.z), p67 = bf2_to_f2(v.w);
        float a[8] = {p01.x, p01.y, p23.x, p23.y, p45.x, p45.y, p67.x, p67.y};
#pragma unroll
        for (int j = 0; j < 8; ++j) {
            int f = sl * 8 + j;
            float z = fmaxf(a[j] * S[f] + T[f], 0.f);
#pragma unroll
            for (int cc = 0; cc < 8; ++cc) lg[cc] += z * sw[f * 8 + cc];
        }
    }
    float mx = lg[0];
#pragma unroll
    for (int cc = 1; cc < 8; ++cc) mx = fmaxf(mx, lg[cc]);
    float sum = 0.f;
#pragma unroll
    for (int cc = 0; cc < 8; ++cc) sum += expf(lg[cc] - mx);
    float lse = logf(sum) + mx;
    float4 o0 = {lg[0] - lse, lg[1] - lse, lg[2] - lse, lg[3] - lse};
    float4 o1 = {lg[4] - lse, lg[5] - lse, lg[6] - lse, lg[7] - lse};
    float4* op = (float4*)(out + (size_t)perm[slot] * 8);
    op[0] = o0;
    op[1] = o1;
}

extern "C" void kernel_launch(void* const* d_in, const int* in_sizes, int n_in,
                              void* d_out, int out_size, void* d_ws, size_t ws_size,
                              hipStream_t stream) {
    const float* x     = (const float*)d_in[0];
    const int*   ei    = (const int*)d_in[1];
    const float* w_in  = (const float*)d_in[2];
    const float* b_in  = (const float*)d_in[3];
    const float* w1    = (const float*)d_in[4];
    const float* b1    = (const float*)d_in[5];
    const float* w2    = (const float*)d_in[6];
    const float* b2    = (const float*)d_in[7];
    const float* w3    = (const float*)d_in[8];
    const float* b3    = (const float*)d_in[9];
    const float* w_o   = (const float*)d_in[10];
    const float* b_o   = (const float*)d_in[11];
    const float* g1    = (const float*)d_in[12];
    const float* be1   = (const float*)d_in[13];
    const float* m1    = (const float*)d_in[14];
    const float* v1    = (const float*)d_in[15];
    const float* g2    = (const float*)d_in[16];
    const float* be2   = (const float*)d_in[17];
    const float* m2    = (const float*)d_in[18];
    const float* v2    = (const float*)d_in[19];
    const float* g3    = (const float*)d_in[20];
    const float* be3   = (const float*)d_in[21];
    const float* m3    = (const float*)d_in[22];
    const float* v3    = (const float*)d_in[23];

    const int N = in_sizes[0] / 128;
    const int E = in_sizes[1] / 2;
    const int K = (N + (1 << BSH) - 1) >> BSH;

    char* p = (char*)d_ws;
    auto alloc = [&](size_t bytes) {
        void* r = (void*)p;
        p += (bytes + 255) & ~(size_t)255;
        return r;
    };
    int*            cnt     = (int*)alloc((size_t)N * 4);
    float*          dinv    = (float*)alloc((size_t)N * 4);
    int*            zbuf    = (int*)alloc(512 * 4);      // bcnt[0..255], dhist[256..320]
    int*            dbuf    = (int*)alloc(256 * 4);      // doff[0..64], doff0[65..129], ebase[130..194]
    int*            perm    = (int*)alloc((size_t)N * 4);
    int*            iperm   = (int*)alloc((size_t)N * 4);
    int*            rowptr2 = (int*)alloc((size_t)(N + 1) * 4);
    float*          dinv2   = (float*)alloc((size_t)N * 4);
    int*            col     = (int*)alloc((size_t)N * CAP * 4);    // id space; reused as a2s
    int*            col2    = (int*)alloc((size_t)(E + N) * 4);    // compact slot-space CSR
    unsigned short* h0s     = (unsigned short*)alloc((size_t)N * 64 * 2);   // reused as t3s
    unsigned short* a1s     = (unsigned short*)alloc((size_t)N * 64 * 2);   // reused as a3s
    unsigned short* h1s     = (unsigned short*)alloc((size_t)N * 128 * 2);  // bins aliases this
    unsigned short* f_in    = (unsigned short*)alloc(8192 * 2);
    unsigned short* f1      = (unsigned short*)alloc(8192 * 2);
    unsigned short* f2      = (unsigned short*)alloc(16384 * 2);
    unsigned short* f3      = (unsigned short*)alloc(8192 * 2);

    int* bcnt  = zbuf;
    int* dhist = zbuf + 256;
    int* doff  = dbuf;
    int* doff0 = dbuf + 65;
    int* ebase = dbuf + 130;
    uint2*          bins = (uint2*)h1s;        // used only before gemm1 writes h1s
    unsigned short* a2s  = (unsigned short*)col; // used only after k_relabel consumes col
    unsigned short* t3s  = h0s;                // h0 dead after agg1
    unsigned short* a3s  = a1s;                // a1 dead after gemm1

    const int gN  = (N + 255) / 256;
    const int gB1 = (E + 2047) / 2048;
    const int gM  = (N + 63) / 64;
    const int gA  = 8 * ((N + 255) / 256);     // slice = blockIdx & 7

    // graph build (id space) + degree sort + relabel to slot space + weight repack
    k_zero<<<2, 256, 0, stream>>>(zbuf, 512);
    k_bin<<<gB1, 256, 0, stream>>>(ei, E, K, bins, bcnt);
    k_place<<<K, 1024, 0, stream>>>(bins, bcnt, col, cnt, dinv, dhist, N);
    k_prefix<<<1, 64, 0, stream>>>(dhist, doff, doff0, ebase, rowptr2 + N);
    k_scatter<<<gN, 256, 0, stream>>>(cnt, doff, perm, N);
    k_iperm<<<gN, 256, 0, stream>>>(perm, iperm, N);
    k_relabel<<<gN, 256, 0, stream>>>(perm, iperm, cnt, dinv, col, doff0, ebase,
                                      col2, rowptr2, dinv2, N);
    k_repack<<<160, 256, 0, stream>>>(w_in, w1, w2, w3, f_in, f1, f2, f3);

    // h0_s = sliced bf16( dinv * relu(x[perm] @ w_in + b_in) )
    mfma_gemm0<<<gM, 256, 0, stream>>>(x, f_in, b_in, dinv2, perm, h0s, N);
    // a1_s = sliced agg(h0_s)
    k_agg<64><<<gA, 256, 0, stream>>>(h0s, a1s, col2, rowptr2, dinv2, N);
    // h1_s = sliced bf16( dinv * relu(bn1(a1 @ w1 + b1)) )
    mfma_gemm1<<<gM, 256, 0, stream>>>(a1s, f1, b1, g1, be1, m1, v1, dinv2, h1s, N);
    // a2_s = sliced agg(h1_s)
    k_agg<128><<<gA, 256, 0, stream>>>(h1s, a2s, col2, rowptr2, dinv2, N);
    // t3_s = sliced bf16( dinv * (relu(bn2(a2@w2+b2)) @ w3) )
    mfma_gemm23<<<gM, 256, 0, stream>>>(a2s, f2, b2, g2, be2, m2, v2, f3, dinv2, t3s, N);
    // a3_s = sliced agg(t3_s)
    k_agg<64><<<gA, 256, 0, stream>>>(t3s, a3s, col2, rowptr2, dinv2, N);
    // out[perm[slot]] = log_softmax( relu(bn3(a3 + b3)) @ w_out + b_out )
    k_final<<<gN, 256, 0, stream>>>(a3s, perm, b3, g3, be3, m3, v3, w_o, b_o, (float*)d_out, N);
}

// Round 11
// 367.990 us; speedup vs baseline: 1.2408x; 1.2408x over previous
//
#include <hip/hip_runtime.h>
#include <math.h>

#define BN_EPS 1e-5f
constexpr int CAP = 64;     // max neighbors/node incl self-loop; deg~Poisson(16), P(>63)~0
constexpr int BSH = 9;      // dst-bucket shift: 512 nodes / bucket
constexpr int BCAP = 10240; // entries per bucket (avg 8192, sd ~90; +22 sigma)

typedef __attribute__((ext_vector_type(8))) short bf16x8;
typedef __attribute__((ext_vector_type(4))) float f32x4;

// ---- bf16 helpers (round-to-nearest-even) ----
__device__ inline unsigned short f2bf(float f) {
    unsigned u = __float_as_uint(f);
    return (unsigned short)((u + 0x7fffu + ((u >> 16) & 1u)) >> 16);
}
__device__ inline float2 bf2_to_f2(unsigned v) {
    float2 r;
    r.x = __uint_as_float(v << 16);
    r.y = __uint_as_float(v & 0xffff0000u);
    return r;
}
__device__ inline void addv(float* a, uint4 v) {
    float2 x0 = bf2_to_f2(v.x), x1 = bf2_to_f2(v.y), x2 = bf2_to_f2(v.z), x3 = bf2_to_f2(v.w);
    a[0] += x0.x; a[1] += x0.y; a[2] += x1.x; a[3] += x1.y;
    a[4] += x2.x; a[5] += x2.y; a[6] += x3.x; a[7] += x3.y;
}

// ---------------- graph build: 2-phase dst-binned counting sort ----------------
// bins entry packed: src (bits 0..19) | dst_local (bits 20..28)  [N<2^20, BSH=9]
__global__ __launch_bounds__(256) void k_zero(int* __restrict__ buf, int L) {
    int i = blockIdx.x * 256 + threadIdx.x;
    if (i < L) buf[i] = 0;
}

__global__ __launch_bounds__(256) void k_bin(const int* __restrict__ ei, int E, int K,
                                             unsigned* __restrict__ bins, int* __restrict__ bcnt) {
    __shared__ int hist[256];
    __shared__ int lbase[256];
    const int tid = threadIdx.x;
    const int e0 = blockIdx.x * 2048;
    hist[tid] = 0;
    __syncthreads();
    int s[8], d[8];
    bool m[8];
#pragma unroll
    for (int i = 0; i < 8; ++i) {
        int e = e0 + i * 256 + tid;
        m[i] = e < E;
        s[i] = m[i] ? ei[e] : 0;
        d[i] = m[i] ? ei[E + e] : 0;
        if (m[i]) atomicAdd(&hist[d[i] >> BSH], 1);
    }
    __syncthreads();
    if (tid < K && hist[tid] > 0) lbase[tid] = atomicAdd(&bcnt[tid], hist[tid]);
    __syncthreads();
    hist[tid] = 0;
    __syncthreads();
#pragma unroll
    for (int i = 0; i < 8; ++i) {
        if (m[i]) {
            int b = d[i] >> BSH;
            int pos = lbase[b] + atomicAdd(&hist[b], 1);
            if (pos < BCAP)
                bins[(size_t)b * BCAP + pos] =
                    (unsigned)s[i] | ((unsigned)(d[i] & ((1 << BSH) - 1)) << 20);
        }
    }
}

__global__ __launch_bounds__(1024) void k_place(const unsigned* __restrict__ bins,
                                                const int* __restrict__ bcnt,
                                                int* __restrict__ col, int* __restrict__ cnt,
                                                float* __restrict__ dinv, int* __restrict__ dhist,
                                                int N) {
    const int b = blockIdx.x;
    const int node0 = b << BSH;
    const int nn = min(1 << BSH, N - node0);
    __shared__ int c2[1 << BSH];
    __shared__ int lh[CAP + 2];
    const int tid = threadIdx.x;
    if (tid < CAP + 2) lh[tid] = 0;
    for (int i = tid; i < nn; i += 1024) {
        c2[i] = 1;
        col[(size_t)(node0 + i) * CAP] = node0 + i;
    }
    __syncthreads();
    const int nb = min(bcnt[b], BCAP);
    const unsigned* __restrict__ bb = bins + (size_t)b * BCAP;
    for (int i = tid; i < nb; i += 1024) {
        unsigned e = bb[i];
        int local = (int)(e >> 20);
        int src = (int)(e & 0xFFFFFu);
        int pos = atomicAdd(&c2[local], 1);
        if (pos < CAP) col[(size_t)(node0 + local) * CAP + pos] = src;
    }
    __syncthreads();
    for (int i = tid; i < nn; i += 1024) {
        int c = c2[i];
        cnt[node0 + i] = c;
        dinv[node0 + i] = rsqrtf((float)c);
        atomicAdd(&lh[min(c, CAP)], 1);
    }
    __syncthreads();
    if (tid <= CAP && lh[tid] > 0) atomicAdd(&dhist[tid], lh[tid]);
}

// exclusive prefix over degree histogram, DESCENDING degree (heavy blocks first)
__global__ void k_prefix(const int* __restrict__ dhist, int* __restrict__ doff) {
    if (threadIdx.x == 0) {
        int s = 0;
        for (int b = CAP; b >= 0; --b) { doff[b] = s; s += dhist[b]; }
    }
}

__global__ __launch_bounds__(256) void k_scatter(const int* __restrict__ cnt, int* __restrict__ doff,
                                                 int* __restrict__ perm, int N) {
    __shared__ int lh[CAP + 2];
    __shared__ int lbase[CAP + 2];
    __shared__ int lpos[CAP + 2];
    const int tid = threadIdx.x;
    if (tid < CAP + 2) { lh[tid] = 0; lpos[tid] = 0; }
    __syncthreads();
    const int i = blockIdx.x * 256 + tid;
    const bool act = i < N;
    int b = 0;
    if (act) { b = min(cnt[i], CAP); atomicAdd(&lh[b], 1); }
    __syncthreads();
    if (tid <= CAP && lh[tid] > 0) lbase[tid] = atomicAdd(&doff[tid], lh[tid]);
    __syncthreads();
    if (act) {
        int p = atomicAdd(&lpos[b], 1);
        perm[lbase[b] + p] = i;
    }
}

// ---------------- weight repack: fp32 [FIN][FOUT] -> bf16 fragment-linear ----------------
__global__ __launch_bounds__(256) void k_repack(
    const float* __restrict__ w_in, const float* __restrict__ w1,
    const float* __restrict__ w2, const float* __restrict__ w3,
    unsigned short* __restrict__ f_in, unsigned short* __restrict__ f1,
    unsigned short* __restrict__ f2, unsigned short* __restrict__ f3)
{
    int idx = blockIdx.x * 256 + threadIdx.x;
    const float* src;
    unsigned short* dst;
    int FOUT, local;
    if (idx < 8192)       { src = w_in; dst = f_in; FOUT = 64;  local = idx; }
    else if (idx < 16384) { src = w1;   dst = f1;   FOUT = 128; local = idx - 8192; }
    else if (idx < 32768) { src = w2;   dst = f2;   FOUT = 128; local = idx - 16384; }
    else                  { src = w3;   dst = f3;   FOUT = 64;  local = idx - 32768; }
    int k = local / FOUT, n = local % FOUT;
    int NT = FOUT >> 4;
    dst[((((k >> 5) * NT + (n >> 4)) * 64) + ((k >> 3) & 3) * 16 + (n & 15)) * 8 + (k & 7)] = f2bf(src[local]);
}

// ---------------- layer 0: h0 = bf16( dinv * relu(x @ w_in + b_in) ) ----------------
__global__ __launch_bounds__(256) void mfma_gemm0(
    const float* __restrict__ in, const unsigned short* __restrict__ wfrag,
    const float* __restrict__ bias, const float* __restrict__ rowscale,
    unsigned short* __restrict__ out, int N)
{
    constexpr int FIN = 128, FOUT = 64, KS = 4, NT = 4, OST = 72;
    __shared__ unsigned short otile[4 * 16 * OST];
    __shared__ float ct[FOUT];
    const int tid = threadIdx.x;
    if (tid < FOUT) ct[tid] = bias[tid];
    __syncthreads();

    const int wid = tid >> 6, lane = tid & 63, q = lane >> 4, m = lane & 15;
    const int rowbase = blockIdx.x * 64 + wid * 16;
    const int rowc = min(rowbase + m, N - 1);
    const bf16x8* __restrict__ wf = (const bf16x8*)wfrag;

    f32x4 accm[NT];
#pragma unroll
    for (int nt = 0; nt < NT; ++nt) accm[nt] = (f32x4){0.f, 0.f, 0.f, 0.f};
#pragma unroll
    for (int ks = 0; ks < KS; ++ks) {
        const float* ap = in + (size_t)rowc * FIN + ks * 32 + q * 8;
        float4 a0 = *(const float4*)ap;
        float4 a1 = *(const float4*)(ap + 4);
        bf16x8 af;
        af[0] = (short)f2bf(a0.x); af[1] = (short)f2bf(a0.y);
        af[2] = (short)f2bf(a0.z); af[3] = (short)f2bf(a0.w);
        af[4] = (short)f2bf(a1.x); af[5] = (short)f2bf(a1.y);
        af[6] = (short)f2bf(a1.z); af[7] = (short)f2bf(a1.w);
#pragma unroll
        for (int nt = 0; nt < NT; ++nt)
            accm[nt] = __builtin_amdgcn_mfma_f32_16x16x32_bf16(af, wf[(ks * NT + nt) * 64 + lane], accm[nt], 0, 0, 0);
    }

    unsigned short* ot = otile + wid * 16 * OST;
    float rs[4];
#pragma unroll
    for (int r = 0; r < 4; ++r) rs[r] = rowscale[min(rowbase + q * 4 + r, N - 1)];
#pragma unroll
    for (int nt = 0; nt < NT; ++nt) {
        int c = nt * 16 + m;
        float t = ct[c];
#pragma unroll
        for (int r = 0; r < 4; ++r) {
            float z = fmaxf(accm[nt][r] + t, 0.f);
            ot[(q * 4 + r) * OST + c] = f2bf(z * rs[r]);
        }
    }
#pragma unroll
    for (int idx = lane; idx < 16 * 8; idx += 64) {
        int rrow = idx >> 3, cc = idx & 7;
        int gr = rowbase + rrow;
        if (gr < N)
            *(uint4*)(out + (size_t)gr * FOUT + cc * 8) = *(const uint4*)&ot[rrow * OST + cc * 8];
    }
}

// ---------------- layer 1: h1 = bf16( dinv * relu(bn1( (A_hat@h0) @ w1 + b1 )) ) ----------------
__global__ __launch_bounds__(256) void agg_mfma1(
    const unsigned short* __restrict__ hin, const unsigned short* __restrict__ wfrag,
    const float* __restrict__ bias, const float* __restrict__ g, const float* __restrict__ beta,
    const float* __restrict__ mm, const float* __restrict__ vv,
    const int* __restrict__ col, const int* __restrict__ cnt, const float* __restrict__ dinv,
    const int* __restrict__ perm,
    unsigned short* __restrict__ out, int N)
{
    constexpr int FIN = 64, FOUT = 128, KS = 2, NT = 8, OST = 136;
    __shared__ unsigned short otile[4 * 16 * OST];
    __shared__ float cs[FOUT], ct[FOUT];
    __shared__ int lperm[64];
    const int tid = threadIdx.x;
    if (tid < FOUT) {
        float s = g[tid] * rsqrtf(vv[tid] + BN_EPS);
        cs[tid] = s;
        ct[tid] = bias[tid] * s + beta[tid] - mm[tid] * s;
    }
    if (tid < 64) lperm[tid] = perm[min((int)(blockIdx.x * 64 + tid), N - 1)];
    __syncthreads();

    const int wid = tid >> 6, lane = tid & 63, q = lane >> 4, m = lane & 15;
    const int rowbase = blockIdx.x * 64 + wid * 16;
    const int node = lperm[wid * 16 + m];
    const int n = (rowbase + m < N) ? min(cnt[node], CAP) : 0;
    const int* __restrict__ c = col + (size_t)node * CAP;

    float acc[KS][8];
#pragma unroll
    for (int i = 0; i < KS; ++i)
#pragma unroll
        for (int e = 0; e < 8; ++e) acc[i][e] = 0.f;

    int p = 0;
    for (; p + 8 <= n; p += 8) {
        int4 ca = *(const int4*)(c + p);
        int4 cb = *(const int4*)(c + p + 4);
        const unsigned short* r0 = hin + (size_t)ca.x * FIN + q * 8;
        const unsigned short* r1 = hin + (size_t)ca.y * FIN + q * 8;
        const unsigned short* r2 = hin + (size_t)ca.z * FIN + q * 8;
        const unsigned short* r3 = hin + (size_t)ca.w * FIN + q * 8;
        const unsigned short* r4 = hin + (size_t)cb.x * FIN + q * 8;
        const unsigned short* r5 = hin + (size_t)cb.y * FIN + q * 8;
        const unsigned short* r6 = hin + (size_t)cb.z * FIN + q * 8;
        const unsigned short* r7 = hin + (size_t)cb.w * FIN + q * 8;
        uint4 v0a = *(const uint4*)r0, v0b = *(const uint4*)(r0 + 32);
        uint4 v1a = *(const uint4*)r1, v1b = *(const uint4*)(r1 + 32);
        uint4 v2a = *(const uint4*)r2, v2b = *(const uint4*)(r2 + 32);
        uint4 v3a = *(const uint4*)r3, v3b = *(const uint4*)(r3 + 32);
        uint4 v4a = *(const uint4*)r4, v4b = *(const uint4*)(r4 + 32);
        uint4 v5a = *(const uint4*)r5, v5b = *(const uint4*)(r5 + 32);
        uint4 v6a = *(const uint4*)r6, v6b = *(const uint4*)(r6 + 32);
        uint4 v7a = *(const uint4*)r7, v7b = *(const uint4*)(r7 + 32);
        addv(acc[0], v0a); addv(acc[1], v0b);
        addv(acc[0], v1a); addv(acc[1], v1b);
        addv(acc[0], v2a); addv(acc[1], v2b);
        addv(acc[0], v3a); addv(acc[1], v3b);
        addv(acc[0], v4a); addv(acc[1], v4b);
        addv(acc[0], v5a); addv(acc[1], v5b);
        addv(acc[0], v6a); addv(acc[1], v6b);
        addv(acc[0], v7a); addv(acc[1], v7b);
    }
    for (; p + 4 <= n; p += 4) {
        int4 ca = *(const int4*)(c + p);
        const unsigned short* r0 = hin + (size_t)ca.x * FIN + q * 8;
        const unsigned short* r1 = hin + (size_t)ca.y * FIN + q * 8;
        const unsigned short* r2 = hin + (size_t)ca.z * FIN + q * 8;
        const unsigned short* r3 = hin + (size_t)ca.w * FIN + q * 8;
        uint4 v0a = *(const uint4*)r0, v0b = *(const uint4*)(r0 + 32);
        uint4 v1a = *(const uint4*)r1, v1b = *(const uint4*)(r1 + 32);
        uint4 v2a = *(const uint4*)r2, v2b = *(const uint4*)(r2 + 32);
        uint4 v3a = *(const uint4*)r3, v3b = *(const uint4*)(r3 + 32);
        addv(acc[0], v0a); addv(acc[1], v0b);
        addv(acc[0], v1a); addv(acc[1], v1b);
        addv(acc[0], v2a); addv(acc[1], v2b);
        addv(acc[0], v3a); addv(acc[1], v3b);
    }
    for (; p < n; ++p) {
        const unsigned short* r0 = hin + (size_t)c[p] * FIN + q * 8;
        addv(acc[0], *(const uint4*)r0);
        addv(acc[1], *(const uint4*)(r0 + 32));
    }

    const float di = dinv[node];
    bf16x8 af[KS];
#pragma unroll
    for (int i = 0; i < KS; ++i)
#pragma unroll
        for (int e = 0; e < 8; ++e) af[i][e] = (short)f2bf(acc[i][e] * di);

    f32x4 accm[NT];
#pragma unroll
    for (int nt = 0; nt < NT; ++nt) accm[nt] = (f32x4){0.f, 0.f, 0.f, 0.f};
    const bf16x8* __restrict__ wf = (const bf16x8*)wfrag;
#pragma unroll
    for (int ks = 0; ks < KS; ++ks)
#pragma unroll
        for (int nt = 0; nt < NT; ++nt)
            accm[nt] = __builtin_amdgcn_mfma_f32_16x16x32_bf16(af[ks], wf[(ks * NT + nt) * 64 + lane], accm[nt], 0, 0, 0);

    unsigned short* ot = otile + wid * 16 * OST;
    float rs[4];
#pragma unroll
    for (int r = 0; r < 4; ++r) rs[r] = dinv[lperm[wid * 16 + q * 4 + r]];
#pragma unroll
    for (int nt = 0; nt < NT; ++nt) {
        int cc = nt * 16 + m;
        float s = cs[cc], t = ct[cc];
#pragma unroll
        for (int r = 0; r < 4; ++r) {
            float z = fmaxf(accm[nt][r] * s + t, 0.f);
            ot[(q * 4 + r) * OST + cc] = f2bf(z * rs[r]);
        }
    }
#pragma unroll
    for (int idx = lane; idx < 16 * (FOUT / 8); idx += 64) {
        int rrow = idx >> 4, cc = idx & 15;
        if (rowbase + rrow < N) {
            int gr = lperm[wid * 16 + rrow];
            *(uint4*)(out + (size_t)gr * FOUT + cc * 8) = *(const uint4*)&ot[rrow * OST + cc * 8];
        }
    }
}

// ---------------- layers 2+3 fused: t3 = bf16( dinv * ( relu(bn2((A_hat@h1)@w2+b2)) @ w3 ) ) ----------------
// 8-neighbor gather batches (32 uint4 = 512 B in flight per lane).
__global__ __launch_bounds__(256) void agg_mfma23(
    const unsigned short* __restrict__ hin, const unsigned short* __restrict__ w2f,
    const float* __restrict__ b2, const float* __restrict__ g2, const float* __restrict__ beta2,
    const float* __restrict__ m2, const float* __restrict__ v2,
    const unsigned short* __restrict__ w3f,
    const int* __restrict__ col, const int* __restrict__ cnt, const float* __restrict__ dinv,
    const int* __restrict__ perm,
    unsigned short* __restrict__ out, int N)
{
    constexpr int FIN = 128, KS = 4, NT1 = 8, NT2 = 4, OST = 136, OST2 = 72;
    __shared__ unsigned short otile[4 * 16 * OST];
    __shared__ float cs[128], ct[128];
    __shared__ int lperm[64];
    const int tid = threadIdx.x;
    if (tid < 128) {
        float s = g2[tid] * rsqrtf(v2[tid] + BN_EPS);
        cs[tid] = s;
        ct[tid] = b2[tid] * s + beta2[tid] - m2[tid] * s;
    }
    if (tid < 64) lperm[tid] = perm[min((int)(blockIdx.x * 64 + tid), N - 1)];
    __syncthreads();

    const int wid = tid >> 6, lane = tid & 63, q = lane >> 4, m = lane & 15;
    const int rowbase = blockIdx.x * 64 + wid * 16;
    const int node = lperm[wid * 16 + m];
    const int n = (rowbase + m < N) ? min(cnt[node], CAP) : 0;
    const int* __restrict__ c = col + (size_t)node * CAP;

    float acc[KS][8];
#pragma unroll
    for (int i = 0; i < KS; ++i)
#pragma unroll
        for (int e = 0; e < 8; ++e) acc[i][e] = 0.f;

    int p = 0;
    for (; p + 8 <= n; p += 8) {
        int4 ca = *(const int4*)(c + p);
        int4 cb = *(const int4*)(c + p + 4);
        const unsigned short* r0 = hin + (size_t)ca.x * FIN + q * 8;
        const unsigned short* r1 = hin + (size_t)ca.y * FIN + q * 8;
        const unsigned short* r2 = hin + (size_t)ca.z * FIN + q * 8;
        const unsigned short* r3 = hin + (size_t)ca.w * FIN + q * 8;
        const unsigned short* r4 = hin + (size_t)cb.x * FIN + q * 8;
        const unsigned short* r5 = hin + (size_t)cb.y * FIN + q * 8;
        const unsigned short* r6 = hin + (size_t)cb.z * FIN + q * 8;
        const unsigned short* r7 = hin + (size_t)cb.w * FIN + q * 8;
        uint4 v0[KS], v1[KS], v2[KS], v3[KS], v4[KS], v5[KS], v6[KS], v7[KS];
#pragma unroll
        for (int i = 0; i < KS; ++i) v0[i] = *(const uint4*)(r0 + i * 32);
#pragma unroll
        for (int i = 0; i < KS; ++i) v1[i] = *(const uint4*)(r1 + i * 32);
#pragma unroll
        for (int i = 0; i < KS; ++i) v2[i] = *(const uint4*)(r2 + i * 32);
#pragma unroll
        for (int i = 0; i < KS; ++i) v3[i] = *(const uint4*)(r3 + i * 32);
#pragma unroll
        for (int i = 0; i < KS; ++i) v4[i] = *(const uint4*)(r4 + i * 32);
#pragma unroll
        for (int i = 0; i < KS; ++i) v5[i] = *(const uint4*)(r5 + i * 32);
#pragma unroll
        for (int i = 0; i < KS; ++i) v6[i] = *(const uint4*)(r6 + i * 32);
#pragma unroll
        for (int i = 0; i < KS; ++i) v7[i] = *(const uint4*)(r7 + i * 32);
#pragma unroll
        for (int i = 0; i < KS; ++i) addv(acc[i], v0[i]);
#pragma unroll
        for (int i = 0; i < KS; ++i) addv(acc[i], v1[i]);
#pragma unroll
        for (int i = 0; i < KS; ++i) addv(acc[i], v2[i]);
#pragma unroll
        for (int i = 0; i < KS; ++i) addv(acc[i], v3[i]);
#pragma unroll
        for (int i = 0; i < KS; ++i) addv(acc[i], v4[i]);
#pragma unroll
        for (int i = 0; i < KS; ++i) addv(acc[i], v5[i]);
#pragma unroll
        for (int i = 0; i < KS; ++i) addv(acc[i], v6[i]);
#pragma unroll
        for (int i = 0; i < KS; ++i) addv(acc[i], v7[i]);
    }
    for (; p + 4 <= n; p += 4) {
        int4 ca = *(const int4*)(c + p);
        const unsigned short* r0 = hin + (size_t)ca.x * FIN + q * 8;
        const unsigned short* r1 = hin + (size_t)ca.y * FIN + q * 8;
        const unsigned short* r2 = hin + (size_t)ca.z * FIN + q * 8;
        const unsigned short* r3 = hin + (size_t)ca.w * FIN + q * 8;
        uint4 v0[KS], v1[KS], v2[KS], v3[KS];
#pragma unroll
        for (int i = 0; i < KS; ++i) v0[i] = *(const uint4*)(r0 + i * 32);
#pragma unroll
        for (int i = 0; i < KS; ++i) v1[i] = *(const uint4*)(r1 + i * 32);
#pragma unroll
        for (int i = 0; i < KS; ++i) v2[i] = *(const uint4*)(r2 + i * 32);
#pragma unroll
        for (int i = 0; i < KS; ++i) v3[i] = *(const uint4*)(r3 + i * 32);
#pragma unroll
        for (int i = 0; i < KS; ++i) addv(acc[i], v0[i]);
#pragma unroll
        for (int i = 0; i < KS; ++i) addv(acc[i], v1[i]);
#pragma unroll
        for (int i = 0; i < KS; ++i) addv(acc[i], v2[i]);
#pragma unroll
        for (int i = 0; i < KS; ++i) addv(acc[i], v3[i]);
    }
    for (; p < n; ++p) {
        const unsigned short* r0 = hin + (size_t)c[p] * FIN + q * 8;
#pragma unroll
        for (int i = 0; i < KS; ++i) addv(acc[i], *(const uint4*)(r0 + i * 32));
    }

    const float di = dinv[node];
    bf16x8 af[KS];
#pragma unroll
    for (int i = 0; i < KS; ++i)
#pragma unroll
        for (int e = 0; e < 8; ++e) af[i][e] = (short)f2bf(acc[i][e] * di);

    // MFMA1: z2 = a2 @ w2
    f32x4 accm[NT1];
#pragma unroll
    for (int nt = 0; nt < NT1; ++nt) accm[nt] = (f32x4){0.f, 0.f, 0.f, 0.f};
    const bf16x8* __restrict__ wf2 = (const bf16x8*)w2f;
#pragma unroll
    for (int ks = 0; ks < KS; ++ks)
#pragma unroll
        for (int nt = 0; nt < NT1; ++nt)
            accm[nt] = __builtin_amdgcn_mfma_f32_16x16x32_bf16(af[ks], wf2[(ks * NT1 + nt) * 64 + lane], accm[nt], 0, 0, 0);

    // h2 = relu(bn2(z2)) -> per-wave LDS tile (C-layout rows -> A-frag reads)
    unsigned short* ot = otile + wid * 16 * OST;
#pragma unroll
    for (int nt = 0; nt < NT1; ++nt) {
        int cc = nt * 16 + m;
        float s = cs[cc], t = ct[cc];
#pragma unroll
        for (int r = 0; r < 4; ++r) {
            float z = fmaxf(accm[nt][r] * s + t, 0.f);
            ot[(q * 4 + r) * OST + cc] = f2bf(z);
        }
    }
    bf16x8 af2[KS];
#pragma unroll
    for (int ks = 0; ks < KS; ++ks)
        af2[ks] = *(const bf16x8*)&ot[m * OST + ks * 32 + q * 8];

    // MFMA2: t3 = h2 @ w3
    f32x4 acc2[NT2];
#pragma unroll
    for (int nt = 0; nt < NT2; ++nt) acc2[nt] = (f32x4){0.f, 0.f, 0.f, 0.f};
    const bf16x8* __restrict__ wf3 = (const bf16x8*)w3f;
#pragma unroll
    for (int ks = 0; ks < KS; ++ks)
#pragma unroll
        for (int nt = 0; nt < NT2; ++nt)
            acc2[nt] = __builtin_amdgcn_mfma_f32_16x16x32_bf16(af2[ks], wf3[(ks * NT2 + nt) * 64 + lane], acc2[nt], 0, 0, 0);

    float rs[4];
#pragma unroll
    for (int r = 0; r < 4; ++r) rs[r] = dinv[lperm[wid * 16 + q * 4 + r]];
#pragma unroll
    for (int nt = 0; nt < NT2; ++nt) {
        int cc = nt * 16 + m;
#pragma unroll
        for (int r = 0; r < 4; ++r)
            ot[(q * 4 + r) * OST2 + cc] = f2bf(acc2[nt][r] * rs[r]);
    }
#pragma unroll
    for (int idx = lane; idx < 16 * 8; idx += 64) {
        int rrow = idx >> 3, cc = idx & 7;
        if (rowbase + rrow < N) {
            int gr = lperm[wid * 16 + rrow];
            *(uint4*)(out + (size_t)gr * 64 + cc * 8) = *(const uint4*)&ot[rrow * OST2 + cc * 8];
        }
    }
}

// ---------------- layer 3 tail fused: out = log_softmax( relu(bn3(A_hat@t3 + b3)) @ w_out + b_out ) ----------------
__global__ __launch_bounds__(256) void agg_final(
    const unsigned short* __restrict__ hin,
    const int* __restrict__ col, const int* __restrict__ cnt, const float* __restrict__ dinv,
    const int* __restrict__ perm,
    const float* __restrict__ b3, const float* __restrict__ g3, const float* __restrict__ beta3,
    const float* __restrict__ m3, const float* __restrict__ v3,
    const float* __restrict__ w_out, const float* __restrict__ b_out,
    float* __restrict__ out, int N)
{
    __shared__ float S[64], T[64], sw[64 * 8], sb[8];
    __shared__ int lperm[64];
    const int tid = threadIdx.x;
    if (tid < 64) {
        float s = g3[tid] * rsqrtf(v3[tid] + BN_EPS);
        S[tid] = s;
        T[tid] = b3[tid] * s + beta3[tid] - m3[tid] * s;
        lperm[tid] = perm[min((int)(blockIdx.x * 64 + tid), N - 1)];
    }
    if (tid < 8) sb[tid] = b_out[tid];
    sw[tid] = w_out[tid];
    sw[tid + 256] = w_out[tid + 256];
    __syncthreads();

    const int wid = tid >> 6, lane = tid & 63, q = lane >> 4, m = lane & 15;
    const int rowbase = blockIdx.x * 64 + wid * 16;
    const int node = lperm[wid * 16 + m];
    const int n = (rowbase + m < N) ? min(cnt[node], CAP) : 0;
    const int* __restrict__ c = col + (size_t)node * CAP;

    float acc[2][8];
#pragma unroll
    for (int i = 0; i < 2; ++i)
#pragma unroll
        for (int e = 0; e < 8; ++e) acc[i][e] = 0.f;

    int p = 0;
    for (; p + 8 <= n; p += 8) {
        int4 ca = *(const int4*)(c + p);
        int4 cb = *(const int4*)(c + p + 4);
        const unsigned short* r0 = hin + (size_t)ca.x * 64 + q * 8;
        const unsigned short* r1 = hin + (size_t)ca.y * 64 + q * 8;
        const unsigned short* r2 = hin + (size_t)ca.z * 64 + q * 8;
        const unsigned short* r3 = hin + (size_t)ca.w * 64 + q * 8;
        const unsigned short* r4 = hin + (size_t)cb.x * 64 + q * 8;
        const unsigned short* r5 = hin + (size_t)cb.y * 64 + q * 8;
        const unsigned short* r6 = hin + (size_t)cb.z * 64 + q * 8;
        const unsigned short* r7 = hin + (size_t)cb.w * 64 + q * 8;
        uint4 v0a = *(const uint4*)r0, v0b = *(const uint4*)(r0 + 32);
        uint4 v1a = *(const uint4*)r1, v1b = *(const uint4*)(r1 + 32);
        uint4 v2a = *(const uint4*)r2, v2b = *(const uint4*)(r2 + 32);
        uint4 v3a = *(const uint4*)r3, v3b = *(const uint4*)(r3 + 32);
        uint4 v4a = *(const uint4*)r4, v4b = *(const uint4*)(r4 + 32);
        uint4 v5a = *(const uint4*)r5, v5b = *(const uint4*)(r5 + 32);
        uint4 v6a = *(const uint4*)r6, v6b = *(const uint4*)(r6 + 32);
        uint4 v7a = *(const uint4*)r7, v7b = *(const uint4*)(r7 + 32);
        addv(acc[0], v0a); addv(acc[1], v0b);
        addv(acc[0], v1a); addv(acc[1], v1b);
        addv(acc[0], v2a); addv(acc[1], v2b);
        addv(acc[0], v3a); addv(acc[1], v3b);
        addv(acc[0], v4a); addv(acc[1], v4b);
        addv(acc[0], v5a); addv(acc[1], v5b);
        addv(acc[0], v6a); addv(acc[1], v6b);
        addv(acc[0], v7a); addv(acc[1], v7b);
    }
    for (; p + 4 <= n; p += 4) {
        int4 ca = *(const int4*)(c + p);
        const unsigned short* r0 = hin + (size_t)ca.x * 64 + q * 8;
        const unsigned short* r1 = hin + (size_t)ca.y * 64 + q * 8;
        const unsigned short* r2 = hin + (size_t)ca.z * 64 + q * 8;
        const unsigned short* r3 = hin + (size_t)ca.w * 64 + q * 8;
        uint4 v0a = *(const uint4*)r0, v0b = *(const uint4*)(r0 + 32);
        uint4 v1a = *(const uint4*)r1, v1b = *(const uint4*)(r1 + 32);
        uint4 v2a = *(const uint4*)r2, v2b = *(const uint4*)(r2 + 32);
        uint4 v3a = *(const uint4*)r3, v3b = *(const uint4*)(r3 + 32);
        addv(acc[0], v0a); addv(acc[1], v0b);
        addv(acc[0], v1a); addv(acc[1], v1b);
        addv(acc[0], v2a); addv(acc[1], v2b);
        addv(acc[0], v3a); addv(acc[1], v3b);
    }
    for (; p < n; ++p) {
        const unsigned short* r0 = hin + (size_t)c[p] * 64 + q * 8;
        addv(acc[0], *(const uint4*)r0);
        addv(acc[1], *(const uint4*)(r0 + 32));
    }

    const float di = dinv[node];
    float lg[8];
#pragma unroll
    for (int cc = 0; cc < 8; ++cc) lg[cc] = 0.f;
#pragma unroll
    for (int i = 0; i < 2; ++i) {
        int fbase = i * 32 + q * 8;
#pragma unroll
        for (int j = 0; j < 8; ++j) {
            int f = fbase + j;
            float z = fmaxf((acc[i][j] * di) * S[f] + T[f], 0.f);
#pragma unroll
            for (int cc = 0; cc < 8; ++cc) lg[cc] += z * sw[f * 8 + cc];
        }
    }
#pragma unroll
    for (int cc = 0; cc < 8; ++cc) {
        lg[cc] += __shfl_xor(lg[cc], 16);
        lg[cc] += __shfl_xor(lg[cc], 32);
    }
    if (q == 0 && rowbase + m < N) {
#pragma unroll
        for (int cc = 0; cc < 8; ++cc) lg[cc] += sb[cc];
        float mx = lg[0];
#pragma unroll
        for (int cc = 1; cc < 8; ++cc) mx = fmaxf(mx, lg[cc]);
        float sum = 0.f;
#pragma unroll
        for (int cc = 0; cc < 8; ++cc) sum += expf(lg[cc] - mx);
        float lse = logf(sum) + mx;
        float4 o0 = {lg[0] - lse, lg[1] - lse, lg[2] - lse, lg[3] - lse};
        float4 o1 = {lg[4] - lse, lg[5] - lse, lg[6] - lse, lg[7] - lse};
        float4* op = (float4*)(out + (size_t)node * 8);
        op[0] = o0;
        op[1] = o1;
    }
}

extern "C" void kernel_launch(void* const* d_in, const int* in_sizes, int n_in,
                              void* d_out, int out_size, void* d_ws, size_t ws_size,
                              hipStream_t stream) {
    const float* x     = (const float*)d_in[0];
    const int*   ei    = (const int*)d_in[1];
    const float* w_in  = (const float*)d_in[2];
    const float* b_in  = (const float*)d_in[3];
    const float* w1    = (const float*)d_in[4];
    const float* b1    = (const float*)d_in[5];
    const float* w2    = (const float*)d_in[6];
    const float* b2    = (const float*)d_in[7];
    const float* w3    = (const float*)d_in[8];
    const float* b3    = (const float*)d_in[9];
    const float* w_o   = (const float*)d_in[10];
    const float* b_o   = (const float*)d_in[11];
    const float* g1    = (const float*)d_in[12];
    const float* be1   = (const float*)d_in[13];
    const float* m1    = (const float*)d_in[14];
    const float* v1    = (const float*)d_in[15];
    const float* g2    = (const float*)d_in[16];
    const float* be2   = (const float*)d_in[17];
    const float* m2    = (const float*)d_in[18];
    const float* v2    = (const float*)d_in[19];
    const float* g3    = (const float*)d_in[20];
    const float* be3   = (const float*)d_in[21];
    const float* m3    = (const float*)d_in[22];
    const float* v3    = (const float*)d_in[23];

    const int N = in_sizes[0] / 128;
    const int E = in_sizes[1] / 2;
    const int K = (N + (1 << BSH) - 1) >> BSH;

    char* p = (char*)d_ws;
    auto alloc = [&](size_t bytes) {
        void* r = (void*)p;
        p += (bytes + 255) & ~(size_t)255;
        return r;
    };
    int*            cnt  = (int*)alloc((size_t)N * 4);
    float*          dinv = (float*)alloc((size_t)N * 4);
    int*            zbuf = (int*)alloc(512 * 4);         // [0..255]=bcnt, [256..321]=dhist
    int*            doff = (int*)alloc(128 * 4);
    int*            perm = (int*)alloc((size_t)N * 4);
    int*            col  = (int*)alloc((size_t)N * CAP * 4);
    unsigned*       bins = (unsigned*)alloc((size_t)K * BCAP * 4);  // packed src|dst_local
    unsigned short* hbA  = (unsigned short*)alloc((size_t)N * 128 * 2);
    unsigned short* hbB  = (unsigned short*)alloc((size_t)N * 128 * 2);
    unsigned short* f_in = (unsigned short*)alloc(8192 * 2);
    unsigned short* f1   = (unsigned short*)alloc(8192 * 2);
    unsigned short* f2   = (unsigned short*)alloc(16384 * 2);
    unsigned short* f3   = (unsigned short*)alloc(8192 * 2);
    int* bcnt  = zbuf;
    int* dhist = zbuf + 256;

    const int gN  = (N + 255) / 256;
    const int gB1 = (E + 2047) / 2048;
    const int gM  = (N + 63) / 64;

    // graph build + degree sort (descending) + weight repack
    k_zero<<<2, 256, 0, stream>>>(zbuf, 512);
    k_bin<<<gB1, 256, 0, stream>>>(ei, E, K, bins, bcnt);
    k_place<<<K, 1024, 0, stream>>>(bins, bcnt, col, cnt, dinv, dhist, N);
    k_prefix<<<1, 64, 0, stream>>>(dhist, doff);
    k_scatter<<<gN, 256, 0, stream>>>(cnt, doff, perm, N);
    k_repack<<<160, 256, 0, stream>>>(w_in, w1, w2, w3, f_in, f1, f2, f3);

    // h0 = bf16( dinv * relu(x @ w_in + b_in) )                     [N,64]  -> hbA
    mfma_gemm0<<<gM, 256, 0, stream>>>(x, f_in, b_in, dinv, hbA, N);
    // h1 = bf16( dinv * relu(bn1( (A_hat@h0) @ w1 + b1 )) )         [N,128] -> hbB
    agg_mfma1<<<gM, 256, 0, stream>>>(hbA, f1, b1, g1, be1, m1, v1, col, cnt, dinv, perm, hbB, N);
    // t3 = bf16( dinv * ( relu(bn2((A_hat@h1)@w2+b2)) @ w3 ) )      [N,64]  -> hbA
    agg_mfma23<<<gM, 256, 0, stream>>>(hbB, f2, b2, g2, be2, m2, v2, f3, col, cnt, dinv, perm, hbA, N);
    // out = log_softmax( relu(bn3(A_hat@t3 + b3)) @ w_out + b_out ) [N,8]
    agg_final<<<gM, 256, 0, stream>>>(hbA, col, cnt, dinv, perm, b3, g3, be3, m3, v3, w_o, b_o, (float*)d_out, N);
}

// Round 12
// 357.548 us; speedup vs baseline: 1.2771x; 1.0292x over previous
//
#include <hip/hip_runtime.h>
#include <math.h>

#define BN_EPS 1e-5f
constexpr int CAP = 64;     // max neighbors/node incl self-loop; deg~Poisson(16), P(>63)~0
constexpr int BSH = 9;      // dst-bucket shift: 512 nodes / bucket
constexpr int BCAP = 10240; // entries per bucket (avg 8192, sd ~90; +22 sigma)

typedef __attribute__((ext_vector_type(8))) short bf16x8;
typedef __attribute__((ext_vector_type(4))) float f32x4;

// ---- bf16 helpers (round-to-nearest-even) ----
__device__ inline unsigned short f2bf(float f) {
    unsigned u = __float_as_uint(f);
    return (unsigned short)((u + 0x7fffu + ((u >> 16) & 1u)) >> 16);
}
__device__ inline float2 bf2_to_f2(unsigned v) {
    float2 r;
    r.x = __uint_as_float(v << 16);
    r.y = __uint_as_float(v & 0xffff0000u);
    return r;
}
__device__ inline void addv(float* a, uint4 v) {
    float2 x0 = bf2_to_f2(v.x), x1 = bf2_to_f2(v.y), x2 = bf2_to_f2(v.z), x3 = bf2_to_f2(v.w);
    a[0] += x0.x; a[1] += x0.y; a[2] += x1.x; a[3] += x1.y;
    a[4] += x2.x; a[5] += x2.y; a[6] += x3.x; a[7] += x3.y;
}

// ---------------- graph build: 2-phase dst-binned counting sort ----------------
// bins entry packed: src (bits 0..19) | dst_local (bits 20..28)  [N<2^20, BSH=9]
__global__ __launch_bounds__(256) void k_zero(int* __restrict__ buf, int L) {
    int i = blockIdx.x * 256 + threadIdx.x;
    if (i < L) buf[i] = 0;
}

__global__ __launch_bounds__(256) void k_bin(const int* __restrict__ ei, int E, int K,
                                             unsigned* __restrict__ bins, int* __restrict__ bcnt) {
    __shared__ int hist[256];
    __shared__ int lbase[256];
    const int tid = threadIdx.x;
    const int e0 = blockIdx.x * 2048;
    hist[tid] = 0;
    __syncthreads();
    int s[8], d[8];
    bool m[8];
#pragma unroll
    for (int i = 0; i < 8; ++i) {
        int e = e0 + i * 256 + tid;
        m[i] = e < E;
        s[i] = m[i] ? ei[e] : 0;
        d[i] = m[i] ? ei[E + e] : 0;
        if (m[i]) atomicAdd(&hist[d[i] >> BSH], 1);
    }
    __syncthreads();
    if (tid < K && hist[tid] > 0) lbase[tid] = atomicAdd(&bcnt[tid], hist[tid]);
    __syncthreads();
    hist[tid] = 0;
    __syncthreads();
#pragma unroll
    for (int i = 0; i < 8; ++i) {
        if (m[i]) {
            int b = d[i] >> BSH;
            int pos = lbase[b] + atomicAdd(&hist[b], 1);
            if (pos < BCAP)
                bins[(size_t)b * BCAP + pos] =
                    (unsigned)s[i] | ((unsigned)(d[i] & ((1 << BSH) - 1)) << 20);
        }
    }
}

__global__ __launch_bounds__(1024) void k_place(const unsigned* __restrict__ bins,
                                                const int* __restrict__ bcnt,
                                                int* __restrict__ col, int* __restrict__ cnt,
                                                float* __restrict__ dinv, int* __restrict__ dhist,
                                                int N) {
    const int b = blockIdx.x;
    const int node0 = b << BSH;
    const int nn = min(1 << BSH, N - node0);
    __shared__ int c2[1 << BSH];
    __shared__ int lh[CAP + 2];
    const int tid = threadIdx.x;
    if (tid < CAP + 2) lh[tid] = 0;
    for (int i = tid; i < nn; i += 1024) {
        c2[i] = 1;
        col[(size_t)(node0 + i) * CAP] = node0 + i;
    }
    __syncthreads();
    const int nb = min(bcnt[b], BCAP);
    const unsigned* __restrict__ bb = bins + (size_t)b * BCAP;
    for (int i = tid; i < nb; i += 1024) {
        unsigned e = bb[i];
        int local = (int)(e >> 20);
        int src = (int)(e & 0xFFFFFu);
        int pos = atomicAdd(&c2[local], 1);
        if (pos < CAP) col[(size_t)(node0 + local) * CAP + pos] = src;
    }
    __syncthreads();
    for (int i = tid; i < nn; i += 1024) {
        int c = c2[i];
        cnt[node0 + i] = c;
        dinv[node0 + i] = rsqrtf((float)c);
        atomicAdd(&lh[min(c, CAP)], 1);
    }
    __syncthreads();
    if (tid <= CAP && lh[tid] > 0) atomicAdd(&dhist[tid], lh[tid]);
}

// exclusive prefix over degree histogram, DESCENDING degree (heavy blocks first)
__global__ void k_prefix(const int* __restrict__ dhist, int* __restrict__ doff) {
    if (threadIdx.x == 0) {
        int s = 0;
        for (int b = CAP; b >= 0; --b) { doff[b] = s; s += dhist[b]; }
    }
}

__global__ __launch_bounds__(256) void k_scatter(const int* __restrict__ cnt, int* __restrict__ doff,
                                                 int* __restrict__ perm, int N) {
    __shared__ int lh[CAP + 2];
    __shared__ int lbase[CAP + 2];
    __shared__ int lpos[CAP + 2];
    const int tid = threadIdx.x;
    if (tid < CAP + 2) { lh[tid] = 0; lpos[tid] = 0; }
    __syncthreads();
    const int i = blockIdx.x * 256 + tid;
    const bool act = i < N;
    int b = 0;
    if (act) { b = min(cnt[i], CAP); atomicAdd(&lh[b], 1); }
    __syncthreads();
    if (tid <= CAP && lh[tid] > 0) lbase[tid] = atomicAdd(&doff[tid], lh[tid]);
    __syncthreads();
    if (act) {
        int p = atomicAdd(&lpos[b], 1);
        perm[lbase[b] + p] = i;
    }
}

// ---------------- weight repack: fp32 [FIN][FOUT] -> bf16 fragment-linear ----------------
__global__ __launch_bounds__(256) void k_repack(
    const float* __restrict__ w_in, const float* __restrict__ w1,
    const float* __restrict__ w2, const float* __restrict__ w3,
    unsigned short* __restrict__ f_in, unsigned short* __restrict__ f1,
    unsigned short* __restrict__ f2, unsigned short* __restrict__ f3)
{
    int idx = blockIdx.x * 256 + threadIdx.x;
    const float* src;
    unsigned short* dst;
    int FOUT, local;
    if (idx < 8192)       { src = w_in; dst = f_in; FOUT = 64;  local = idx; }
    else if (idx < 16384) { src = w1;   dst = f1;   FOUT = 128; local = idx - 8192; }
    else if (idx < 32768) { src = w2;   dst = f2;   FOUT = 128; local = idx - 16384; }
    else                  { src = w3;   dst = f3;   FOUT = 64;  local = idx - 32768; }
    int k = local / FOUT, n = local % FOUT;
    int NT = FOUT >> 4;
    dst[((((k >> 5) * NT + (n >> 4)) * 64) + ((k >> 3) & 3) * 16 + (n & 15)) * 8 + (k & 7)] = f2bf(src[local]);
}

// ---------------- layer 0: h0 = bf16( dinv * relu(x @ w_in + b_in) ) ----------------
__global__ __launch_bounds__(256) void mfma_gemm0(
    const float* __restrict__ in, const unsigned short* __restrict__ wfrag,
    const float* __restrict__ bias, const float* __restrict__ rowscale,
    unsigned short* __restrict__ out, int N)
{
    constexpr int FIN = 128, FOUT = 64, KS = 4, NT = 4, OST = 72;
    __shared__ unsigned short otile[4 * 16 * OST];
    __shared__ float ct[FOUT];
    const int tid = threadIdx.x;
    if (tid < FOUT) ct[tid] = bias[tid];
    __syncthreads();

    const int wid = tid >> 6, lane = tid & 63, q = lane >> 4, m = lane & 15;
    const int rowbase = blockIdx.x * 64 + wid * 16;
    const int rowc = min(rowbase + m, N - 1);
    const bf16x8* __restrict__ wf = (const bf16x8*)wfrag;

    f32x4 accm[NT];
#pragma unroll
    for (int nt = 0; nt < NT; ++nt) accm[nt] = (f32x4){0.f, 0.f, 0.f, 0.f};
#pragma unroll
    for (int ks = 0; ks < KS; ++ks) {
        const float* ap = in + (size_t)rowc * FIN + ks * 32 + q * 8;
        float4 a0 = *(const float4*)ap;
        float4 a1 = *(const float4*)(ap + 4);
        bf16x8 af;
        af[0] = (short)f2bf(a0.x); af[1] = (short)f2bf(a0.y);
        af[2] = (short)f2bf(a0.z); af[3] = (short)f2bf(a0.w);
        af[4] = (short)f2bf(a1.x); af[5] = (short)f2bf(a1.y);
        af[6] = (short)f2bf(a1.z); af[7] = (short)f2bf(a1.w);
#pragma unroll
        for (int nt = 0; nt < NT; ++nt)
            accm[nt] = __builtin_amdgcn_mfma_f32_16x16x32_bf16(af, wf[(ks * NT + nt) * 64 + lane], accm[nt], 0, 0, 0);
    }

    unsigned short* ot = otile + wid * 16 * OST;
    float rs[4];
#pragma unroll
    for (int r = 0; r < 4; ++r) rs[r] = rowscale[min(rowbase + q * 4 + r, N - 1)];
#pragma unroll
    for (int nt = 0; nt < NT; ++nt) {
        int c = nt * 16 + m;
        float t = ct[c];
#pragma unroll
        for (int r = 0; r < 4; ++r) {
            float z = fmaxf(accm[nt][r] + t, 0.f);
            ot[(q * 4 + r) * OST + c] = f2bf(z * rs[r]);
        }
    }
#pragma unroll
    for (int idx = lane; idx < 16 * 8; idx += 64) {
        int rrow = idx >> 3, cc = idx & 7;
        int gr = rowbase + rrow;
        if (gr < N)
            *(uint4*)(out + (size_t)gr * FOUT + cc * 8) = *(const uint4*)&ot[rrow * OST + cc * 8];
    }
}

// ---------------- layer 1: h1 = bf16( dinv * relu(bn1( (A_hat@h0) @ w1 + b1 )) ) ----------------
// Gather-in-fragment, degree-equalized, 8-neighbor batches (16 uint4 in flight).
__global__ __launch_bounds__(256) void agg_mfma1(
    const unsigned short* __restrict__ hin, const unsigned short* __restrict__ wfrag,
    const float* __restrict__ bias, const float* __restrict__ g, const float* __restrict__ beta,
    const float* __restrict__ mm, const float* __restrict__ vv,
    const int* __restrict__ col, const int* __restrict__ cnt, const float* __restrict__ dinv,
    const int* __restrict__ perm,
    unsigned short* __restrict__ out, int N)
{
    constexpr int FIN = 64, FOUT = 128, KS = 2, NT = 8, OST = 136;
    __shared__ unsigned short otile[4 * 16 * OST];
    __shared__ float cs[FOUT], ct[FOUT];
    __shared__ int lperm[64];
    const int tid = threadIdx.x;
    if (tid < FOUT) {
        float s = g[tid] * rsqrtf(vv[tid] + BN_EPS);
        cs[tid] = s;
        ct[tid] = bias[tid] * s + beta[tid] - mm[tid] * s;
    }
    if (tid < 64) lperm[tid] = perm[min((int)(blockIdx.x * 64 + tid), N - 1)];
    __syncthreads();

    const int wid = tid >> 6, lane = tid & 63, q = lane >> 4, m = lane & 15;
    const int rowbase = blockIdx.x * 64 + wid * 16;
    const int node = lperm[wid * 16 + m];
    const int n = (rowbase + m < N) ? min(cnt[node], CAP) : 0;
    const int* __restrict__ c = col + (size_t)node * CAP;

    float acc[KS][8];
#pragma unroll
    for (int i = 0; i < KS; ++i)
#pragma unroll
        for (int e = 0; e < 8; ++e) acc[i][e] = 0.f;

    int p = 0;
    for (; p + 8 <= n; p += 8) {
        int4 ca = *(const int4*)(c + p);
        int4 cb = *(const int4*)(c + p + 4);
        const unsigned short* r0 = hin + (size_t)ca.x * FIN + q * 8;
        const unsigned short* r1 = hin + (size_t)ca.y * FIN + q * 8;
        const unsigned short* r2 = hin + (size_t)ca.z * FIN + q * 8;
        const unsigned short* r3 = hin + (size_t)ca.w * FIN + q * 8;
        const unsigned short* r4 = hin + (size_t)cb.x * FIN + q * 8;
        const unsigned short* r5 = hin + (size_t)cb.y * FIN + q * 8;
        const unsigned short* r6 = hin + (size_t)cb.z * FIN + q * 8;
        const unsigned short* r7 = hin + (size_t)cb.w * FIN + q * 8;
        uint4 v0a = *(const uint4*)r0, v0b = *(const uint4*)(r0 + 32);
        uint4 v1a = *(const uint4*)r1, v1b = *(const uint4*)(r1 + 32);
        uint4 v2a = *(const uint4*)r2, v2b = *(const uint4*)(r2 + 32);
        uint4 v3a = *(const uint4*)r3, v3b = *(const uint4*)(r3 + 32);
        uint4 v4a = *(const uint4*)r4, v4b = *(const uint4*)(r4 + 32);
        uint4 v5a = *(const uint4*)r5, v5b = *(const uint4*)(r5 + 32);
        uint4 v6a = *(const uint4*)r6, v6b = *(const uint4*)(r6 + 32);
        uint4 v7a = *(const uint4*)r7, v7b = *(const uint4*)(r7 + 32);
        addv(acc[0], v0a); addv(acc[1], v0b);
        addv(acc[0], v1a); addv(acc[1], v1b);
        addv(acc[0], v2a); addv(acc[1], v2b);
        addv(acc[0], v3a); addv(acc[1], v3b);
        addv(acc[0], v4a); addv(acc[1], v4b);
        addv(acc[0], v5a); addv(acc[1], v5b);
        addv(acc[0], v6a); addv(acc[1], v6b);
        addv(acc[0], v7a); addv(acc[1], v7b);
    }
    for (; p + 4 <= n; p += 4) {
        int4 ca = *(const int4*)(c + p);
        const unsigned short* r0 = hin + (size_t)ca.x * FIN + q * 8;
        const unsigned short* r1 = hin + (size_t)ca.y * FIN + q * 8;
        const unsigned short* r2 = hin + (size_t)ca.z * FIN + q * 8;
        const unsigned short* r3 = hin + (size_t)ca.w * FIN + q * 8;
        uint4 v0a = *(const uint4*)r0, v0b = *(const uint4*)(r0 + 32);
        uint4 v1a = *(const uint4*)r1, v1b = *(const uint4*)(r1 + 32);
        uint4 v2a = *(const uint4*)r2, v2b = *(const uint4*)(r2 + 32);
        uint4 v3a = *(const uint4*)r3, v3b = *(const uint4*)(r3 + 32);
        addv(acc[0], v0a); addv(acc[1], v0b);
        addv(acc[0], v1a); addv(acc[1], v1b);
        addv(acc[0], v2a); addv(acc[1], v2b);
        addv(acc[0], v3a); addv(acc[1], v3b);
    }
    for (; p < n; ++p) {
        const unsigned short* r0 = hin + (size_t)c[p] * FIN + q * 8;
        addv(acc[0], *(const uint4*)r0);
        addv(acc[1], *(const uint4*)(r0 + 32));
    }

    const float di = dinv[node];
    bf16x8 af[KS];
#pragma unroll
    for (int i = 0; i < KS; ++i)
#pragma unroll
        for (int e = 0; e < 8; ++e) af[i][e] = (short)f2bf(acc[i][e] * di);

    f32x4 accm[NT];
#pragma unroll
    for (int nt = 0; nt < NT; ++nt) accm[nt] = (f32x4){0.f, 0.f, 0.f, 0.f};
    const bf16x8* __restrict__ wf = (const bf16x8*)wfrag;
#pragma unroll
    for (int ks = 0; ks < KS; ++ks)
#pragma unroll
        for (int nt = 0; nt < NT; ++nt)
            accm[nt] = __builtin_amdgcn_mfma_f32_16x16x32_bf16(af[ks], wf[(ks * NT + nt) * 64 + lane], accm[nt], 0, 0, 0);

    unsigned short* ot = otile + wid * 16 * OST;
    float rs[4];
#pragma unroll
    for (int r = 0; r < 4; ++r) rs[r] = dinv[lperm[wid * 16 + q * 4 + r]];
#pragma unroll
    for (int nt = 0; nt < NT; ++nt) {
        int cc = nt * 16 + m;
        float s = cs[cc], t = ct[cc];
#pragma unroll
        for (int r = 0; r < 4; ++r) {
            float z = fmaxf(accm[nt][r] * s + t, 0.f);
            ot[(q * 4 + r) * OST + cc] = f2bf(z * rs[r]);
        }
    }
#pragma unroll
    for (int idx = lane; idx < 16 * (FOUT / 8); idx += 64) {
        int rrow = idx >> 4, cc = idx & 15;
        if (rowbase + rrow < N) {
            int gr = lperm[wid * 16 + rrow];
            *(uint4*)(out + (size_t)gr * FOUT + cc * 8) = *(const uint4*)&ot[rrow * OST + cc * 8];
        }
    }
}

// ---------------- layers 2+3 fused: t3 = bf16( dinv * ( relu(bn2((A_hat@h1)@w2+b2)) @ w3 ) ) ----------------
// 4-neighbor gather batches (16 uint4 in flight) — R9 sweet spot (VGPR ~104).
__global__ __launch_bounds__(256) void agg_mfma23(
    const unsigned short* __restrict__ hin, const unsigned short* __restrict__ w2f,
    const float* __restrict__ b2, const float* __restrict__ g2, const float* __restrict__ beta2,
    const float* __restrict__ m2, const float* __restrict__ v2,
    const unsigned short* __restrict__ w3f,
    const int* __restrict__ col, const int* __restrict__ cnt, const float* __restrict__ dinv,
    const int* __restrict__ perm,
    unsigned short* __restrict__ out, int N)
{
    constexpr int FIN = 128, KS = 4, NT1 = 8, NT2 = 4, OST = 136, OST2 = 72;
    __shared__ unsigned short otile[4 * 16 * OST];
    __shared__ float cs[128], ct[128];
    __shared__ int lperm[64];
    const int tid = threadIdx.x;
    if (tid < 128) {
        float s = g2[tid] * rsqrtf(v2[tid] + BN_EPS);
        cs[tid] = s;
        ct[tid] = b2[tid] * s + beta2[tid] - m2[tid] * s;
    }
    if (tid < 64) lperm[tid] = perm[min((int)(blockIdx.x * 64 + tid), N - 1)];
    __syncthreads();

    const int wid = tid >> 6, lane = tid & 63, q = lane >> 4, m = lane & 15;
    const int rowbase = blockIdx.x * 64 + wid * 16;
    const int node = lperm[wid * 16 + m];
    const int n = (rowbase + m < N) ? min(cnt[node], CAP) : 0;
    const int* __restrict__ c = col + (size_t)node * CAP;

    float acc[KS][8];
#pragma unroll
    for (int i = 0; i < KS; ++i)
#pragma unroll
        for (int e = 0; e < 8; ++e) acc[i][e] = 0.f;

    int p = 0;
    for (; p + 4 <= n; p += 4) {
        int4 ca = *(const int4*)(c + p);
        const unsigned short* r0 = hin + (size_t)ca.x * FIN + q * 8;
        const unsigned short* r1 = hin + (size_t)ca.y * FIN + q * 8;
        const unsigned short* r2 = hin + (size_t)ca.z * FIN + q * 8;
        const unsigned short* r3 = hin + (size_t)ca.w * FIN + q * 8;
        uint4 v0[KS], v1[KS], v2[KS], v3[KS];
#pragma unroll
        for (int i = 0; i < KS; ++i) v0[i] = *(const uint4*)(r0 + i * 32);
#pragma unroll
        for (int i = 0; i < KS; ++i) v1[i] = *(const uint4*)(r1 + i * 32);
#pragma unroll
        for (int i = 0; i < KS; ++i) v2[i] = *(const uint4*)(r2 + i * 32);
#pragma unroll
        for (int i = 0; i < KS; ++i) v3[i] = *(const uint4*)(r3 + i * 32);
#pragma unroll
        for (int i = 0; i < KS; ++i) addv(acc[i], v0[i]);
#pragma unroll
        for (int i = 0; i < KS; ++i) addv(acc[i], v1[i]);
#pragma unroll
        for (int i = 0; i < KS; ++i) addv(acc[i], v2[i]);
#pragma unroll
        for (int i = 0; i < KS; ++i) addv(acc[i], v3[i]);
    }
    for (; p < n; ++p) {
        const unsigned short* r0 = hin + (size_t)c[p] * FIN + q * 8;
#pragma unroll
        for (int i = 0; i < KS; ++i) addv(acc[i], *(const uint4*)(r0 + i * 32));
    }

    const float di = dinv[node];
    bf16x8 af[KS];
#pragma unroll
    for (int i = 0; i < KS; ++i)
#pragma unroll
        for (int e = 0; e < 8; ++e) af[i][e] = (short)f2bf(acc[i][e] * di);

    // MFMA1: z2 = a2 @ w2
    f32x4 accm[NT1];
#pragma unroll
    for (int nt = 0; nt < NT1; ++nt) accm[nt] = (f32x4){0.f, 0.f, 0.f, 0.f};
    const bf16x8* __restrict__ wf2 = (const bf16x8*)w2f;
#pragma unroll
    for (int ks = 0; ks < KS; ++ks)
#pragma unroll
        for (int nt = 0; nt < NT1; ++nt)
            accm[nt] = __builtin_amdgcn_mfma_f32_16x16x32_bf16(af[ks], wf2[(ks * NT1 + nt) * 64 + lane], accm[nt], 0, 0, 0);

    // h2 = relu(bn2(z2)) -> per-wave LDS tile (C-layout rows -> A-frag reads)
    unsigned short* ot = otile + wid * 16 * OST;
#pragma unroll
    for (int nt = 0; nt < NT1; ++nt) {
        int cc = nt * 16 + m;
        float s = cs[cc], t = ct[cc];
#pragma unroll
        for (int r = 0; r < 4; ++r) {
            float z = fmaxf(accm[nt][r] * s + t, 0.f);
            ot[(q * 4 + r) * OST + cc] = f2bf(z);
        }
    }
    bf16x8 af2[KS];
#pragma unroll
    for (int ks = 0; ks < KS; ++ks)
        af2[ks] = *(const bf16x8*)&ot[m * OST + ks * 32 + q * 8];

    // MFMA2: t3 = h2 @ w3
    f32x4 acc2[NT2];
#pragma unroll
    for (int nt = 0; nt < NT2; ++nt) acc2[nt] = (f32x4){0.f, 0.f, 0.f, 0.f};
    const bf16x8* __restrict__ wf3 = (const bf16x8*)w3f;
#pragma unroll
    for (int ks = 0; ks < KS; ++ks)
#pragma unroll
        for (int nt = 0; nt < NT2; ++nt)
            acc2[nt] = __builtin_amdgcn_mfma_f32_16x16x32_bf16(af2[ks], wf3[(ks * NT2 + nt) * 64 + lane], acc2[nt], 0, 0, 0);

    float rs[4];
#pragma unroll
    for (int r = 0; r < 4; ++r) rs[r] = dinv[lperm[wid * 16 + q * 4 + r]];
#pragma unroll
    for (int nt = 0; nt < NT2; ++nt) {
        int cc = nt * 16 + m;
#pragma unroll
        for (int r = 0; r < 4; ++r)
            ot[(q * 4 + r) * OST2 + cc] = f2bf(acc2[nt][r] * rs[r]);
    }
#pragma unroll
    for (int idx = lane; idx < 16 * 8; idx += 64) {
        int rrow = idx >> 3, cc = idx & 7;
        if (rowbase + rrow < N) {
            int gr = lperm[wid * 16 + rrow];
            *(uint4*)(out + (size_t)gr * 64 + cc * 8) = *(const uint4*)&ot[rrow * OST2 + cc * 8];
        }
    }
}

// ---------------- layer 3 tail fused: out = log_softmax( relu(bn3(A_hat@t3 + b3)) @ w_out + b_out ) ----------------
__global__ __launch_bounds__(256) void agg_final(
    const unsigned short* __restrict__ hin,
    const int* __restrict__ col, const int* __restrict__ cnt, const float* __restrict__ dinv,
    const int* __restrict__ perm,
    const float* __restrict__ b3, const float* __restrict__ g3, const float* __restrict__ beta3,
    const float* __restrict__ m3, const float* __restrict__ v3,
    const float* __restrict__ w_out, const float* __restrict__ b_out,
    float* __restrict__ out, int N)
{
    __shared__ float S[64], T[64], sw[64 * 8], sb[8];
    __shared__ int lperm[64];
    const int tid = threadIdx.x;
    if (tid < 64) {
        float s = g3[tid] * rsqrtf(v3[tid] + BN_EPS);
        S[tid] = s;
        T[tid] = b3[tid] * s + beta3[tid] - m3[tid] * s;
        lperm[tid] = perm[min((int)(blockIdx.x * 64 + tid), N - 1)];
    }
    if (tid < 8) sb[tid] = b_out[tid];
    sw[tid] = w_out[tid];
    sw[tid + 256] = w_out[tid + 256];
    __syncthreads();

    const int wid = tid >> 6, lane = tid & 63, q = lane >> 4, m = lane & 15;
    const int rowbase = blockIdx.x * 64 + wid * 16;
    const int node = lperm[wid * 16 + m];
    const int n = (rowbase + m < N) ? min(cnt[node], CAP) : 0;
    const int* __restrict__ c = col + (size_t)node * CAP;

    float acc[2][8];
#pragma unroll
    for (int i = 0; i < 2; ++i)
#pragma unroll
        for (int e = 0; e < 8; ++e) acc[i][e] = 0.f;

    int p = 0;
    for (; p + 8 <= n; p += 8) {
        int4 ca = *(const int4*)(c + p);
        int4 cb = *(const int4*)(c + p + 4);
        const unsigned short* r0 = hin + (size_t)ca.x * 64 + q * 8;
        const unsigned short* r1 = hin + (size_t)ca.y * 64 + q * 8;
        const unsigned short* r2 = hin + (size_t)ca.z * 64 + q * 8;
        const unsigned short* r3 = hin + (size_t)ca.w * 64 + q * 8;
        const unsigned short* r4 = hin + (size_t)cb.x * 64 + q * 8;
        const unsigned short* r5 = hin + (size_t)cb.y * 64 + q * 8;
        const unsigned short* r6 = hin + (size_t)cb.z * 64 + q * 8;
        const unsigned short* r7 = hin + (size_t)cb.w * 64 + q * 8;
        uint4 v0a = *(const uint4*)r0, v0b = *(const uint4*)(r0 + 32);
        uint4 v1a = *(const uint4*)r1, v1b = *(const uint4*)(r1 + 32);
        uint4 v2a = *(const uint4*)r2, v2b = *(const uint4*)(r2 + 32);
        uint4 v3a = *(const uint4*)r3, v3b = *(const uint4*)(r3 + 32);
        uint4 v4a = *(const uint4*)r4, v4b = *(const uint4*)(r4 + 32);
        uint4 v5a = *(const uint4*)r5, v5b = *(const uint4*)(r5 + 32);
        uint4 v6a = *(const uint4*)r6, v6b = *(const uint4*)(r6 + 32);
        uint4 v7a = *(const uint4*)r7, v7b = *(const uint4*)(r7 + 32);
        addv(acc[0], v0a); addv(acc[1], v0b);
        addv(acc[0], v1a); addv(acc[1], v1b);
        addv(acc[0], v2a); addv(acc[1], v2b);
        addv(acc[0], v3a); addv(acc[1], v3b);
        addv(acc[0], v4a); addv(acc[1], v4b);
        addv(acc[0], v5a); addv(acc[1], v5b);
        addv(acc[0], v6a); addv(acc[1], v6b);
        addv(acc[0], v7a); addv(acc[1], v7b);
    }
    for (; p + 4 <= n; p += 4) {
        int4 ca = *(const int4*)(c + p);
        const unsigned short* r0 = hin + (size_t)ca.x * 64 + q * 8;
        const unsigned short* r1 = hin + (size_t)ca.y * 64 + q * 8;
        const unsigned short* r2 = hin + (size_t)ca.z * 64 + q * 8;
        const unsigned short* r3 = hin + (size_t)ca.w * 64 + q * 8;
        uint4 v0a = *(const uint4*)r0, v0b = *(const uint4*)(r0 + 32);
        uint4 v1a = *(const uint4*)r1, v1b = *(const uint4*)(r1 + 32);
        uint4 v2a = *(const uint4*)r2, v2b = *(const uint4*)(r2 + 32);
        uint4 v3a = *(const uint4*)r3, v3b = *(const uint4*)(r3 + 32);
        addv(acc[0], v0a); addv(acc[1], v0b);
        addv(acc[0], v1a); addv(acc[1], v1b);
        addv(acc[0], v2a); addv(acc[1], v2b);
        addv(acc[0], v3a); addv(acc[1], v3b);
    }
    for (; p < n; ++p) {
        const unsigned short* r0 = hin + (size_t)c[p] * 64 + q * 8;
        addv(acc[0], *(const uint4*)r0);
        addv(acc[1], *(const uint4*)(r0 + 32));
    }

    const float di = dinv[node];
    float lg[8];
#pragma unroll
    for (int cc = 0; cc < 8; ++cc) lg[cc] = 0.f;
#pragma unroll
    for (int i = 0; i < 2; ++i) {
        int fbase = i * 32 + q * 8;
#pragma unroll
        for (int j = 0; j < 8; ++j) {
            int f = fbase + j;
            float z = fmaxf((acc[i][j] * di) * S[f] + T[f], 0.f);
#pragma unroll
            for (int cc = 0; cc < 8; ++cc) lg[cc] += z * sw[f * 8 + cc];
        }
    }
#pragma unroll
    for (int cc = 0; cc < 8; ++cc) {
        lg[cc] += __shfl_xor(lg[cc], 16);
        lg[cc] += __shfl_xor(lg[cc], 32);
    }
    if (q == 0 && rowbase + m < N) {
#pragma unroll
        for (int cc = 0; cc < 8; ++cc) lg[cc] += sb[cc];
        float mx = lg[0];
#pragma unroll
        for (int cc = 1; cc < 8; ++cc) mx = fmaxf(mx, lg[cc]);
        float sum = 0.f;
#pragma unroll
        for (int cc = 0; cc < 8; ++cc) sum += expf(lg[cc] - mx);
        float lse = logf(sum) + mx;
        float4 o0 = {lg[0] - lse, lg[1] - lse, lg[2] - lse, lg[3] - lse};
        float4 o1 = {lg[4] - lse, lg[5] - lse, lg[6] - lse, lg[7] - lse};
        float4* op = (float4*)(out + (size_t)node * 8);
        op[0] = o0;
        op[1] = o1;
    }
}

extern "C" void kernel_launch(void* const* d_in, const int* in_sizes, int n_in,
                              void* d_out, int out_size, void* d_ws, size_t ws_size,
                              hipStream_t stream) {
    const float* x     = (const float*)d_in[0];
    const int*   ei    = (const int*)d_in[1];
    const float* w_in  = (const float*)d_in[2];
    const float* b_in  = (const float*)d_in[3];
    const float* w1    = (const float*)d_in[4];
    const float* b1    = (const float*)d_in[5];
    const float* w2    = (const float*)d_in[6];
    const float* b2    = (const float*)d_in[7];
    const float* w3    = (const float*)d_in[8];
    const float* b3    = (const float*)d_in[9];
    const float* w_o   = (const float*)d_in[10];
    const float* b_o   = (const float*)d_in[11];
    const float* g1    = (const float*)d_in[12];
    const float* be1   = (const float*)d_in[13];
    const float* m1    = (const float*)d_in[14];
    const float* v1    = (const float*)d_in[15];
    const float* g2    = (const float*)d_in[16];
    const float* be2   = (const float*)d_in[17];
    const float* m2    = (const float*)d_in[18];
    const float* v2    = (const float*)d_in[19];
    const float* g3    = (const float*)d_in[20];
    const float* be3   = (const float*)d_in[21];
    const float* m3    = (const float*)d_in[22];
    const float* v3    = (const float*)d_in[23];

    const int N = in_sizes[0] / 128;
    const int E = in_sizes[1] / 2;
    const int K = (N + (1 << BSH) - 1) >> BSH;

    char* p = (char*)d_ws;
    auto alloc = [&](size_t bytes) {
        void* r = (void*)p;
        p += (bytes + 255) & ~(size_t)255;
        return r;
    };
    int*            cnt  = (int*)alloc((size_t)N * 4);
    float*          dinv = (float*)alloc((size_t)N * 4);
    int*            zbuf = (int*)alloc(512 * 4);         // [0..255]=bcnt, [256..321]=dhist
    int*            doff = (int*)alloc(128 * 4);
    int*            perm = (int*)alloc((size_t)N * 4);
    int*            col  = (int*)alloc((size_t)N * CAP * 4);
    unsigned*       bins = (unsigned*)alloc((size_t)K * BCAP * 4);  // packed src|dst_local
    unsigned short* hbA  = (unsigned short*)alloc((size_t)N * 128 * 2);
    unsigned short* hbB  = (unsigned short*)alloc((size_t)N * 128 * 2);
    unsigned short* f_in = (unsigned short*)alloc(8192 * 2);
    unsigned short* f1   = (unsigned short*)alloc(8192 * 2);
    unsigned short* f2   = (unsigned short*)alloc(16384 * 2);
    unsigned short* f3   = (unsigned short*)alloc(8192 * 2);
    int* bcnt  = zbuf;
    int* dhist = zbuf + 256;

    const int gN  = (N + 255) / 256;
    const int gB1 = (E + 2047) / 2048;
    const int gM  = (N + 63) / 64;

    // graph build + degree sort (descending) + weight repack
    k_zero<<<2, 256, 0, stream>>>(zbuf, 512);
    k_bin<<<gB1, 256, 0, stream>>>(ei, E, K, bins, bcnt);
    k_place<<<K, 1024, 0, stream>>>(bins, bcnt, col, cnt, dinv, dhist, N);
    k_prefix<<<1, 64, 0, stream>>>(dhist, doff);
    k_scatter<<<gN, 256, 0, stream>>>(cnt, doff, perm, N);
    k_repack<<<160, 256, 0, stream>>>(w_in, w1, w2, w3, f_in, f1, f2, f3);

    // h0 = bf16( dinv * relu(x @ w_in + b_in) )                     [N,64]  -> hbA
    mfma_gemm0<<<gM, 256, 0, stream>>>(x, f_in, b_in, dinv, hbA, N);
    // h1 = bf16( dinv * relu(bn1( (A_hat@h0) @ w1 + b1 )) )         [N,128] -> hbB
    agg_mfma1<<<gM, 256, 0, stream>>>(hbA, f1, b1, g1, be1, m1, v1, col, cnt, dinv, perm, hbB, N);
    // t3 = bf16( dinv * ( relu(bn2((A_hat@h1)@w2+b2)) @ w3 ) )      [N,64]  -> hbA
    agg_mfma23<<<gM, 256, 0, stream>>>(hbB, f2, b2, g2, be2, m2, v2, f3, col, cnt, dinv, perm, hbA, N);
    // out = log_softmax( relu(bn3(A_hat@t3 + b3)) @ w_out + b_out ) [N,8]
    agg_final<<<gM, 256, 0, stream>>>(hbA, col, cnt, dinv, perm, b3, g3, be3, m3, v3, w_o, b_o, (float*)d_out, N);
}